// Round 15
// baseline (3086.650 us; speedup 1.0000x reference)
//
#include <hip/hip_runtime.h>
#include <hip/hip_bf16.h>
#include <cstdint>
#include <math.h>

using bf16 = __hip_bfloat16;
typedef __attribute__((ext_vector_type(4))) float f32x4;
typedef __attribute__((ext_vector_type(8))) short s16x8;
typedef __attribute__((ext_vector_type(4))) short s16x4;

#define AS3(p) ((__attribute__((address_space(3))) void *)(p))
#define AS1(p) ((const __attribute__((address_space(1))) void *)(p))

static constexpr int Himg = 256, Wimg = 256, Bimg = 4;
static constexpr int HWimg = Himg * Wimg;
static constexpr int Ttok = Bimg * HWimg;   // 262144 tokens

__device__ __forceinline__ void gld16(bf16* lds, const bf16* g) {
  __builtin_amdgcn_global_load_lds(AS1(g), AS3(lds), 16, 0, 0);
}

__device__ __forceinline__ unsigned short f2u(float f) {
  bf16 b = __float2bfloat16(f);
  unsigned short u; __builtin_memcpy(&u, &b, 2); return u;
}

// XCD-chunked remap (1D): hw round-robin (bid%8) -> contiguous logical chunks.
__device__ __forceinline__ int remap_lin(int bid, int total) {
  return (bid & 7) * (total >> 3) + (bid >> 3);
}
__device__ __forceinline__ void remap_tile(int bid, int total, int NY, int BMv, int& t0, int& n0) {
  int lin = remap_lin(bid, total);
  t0 = (lin / NY) * BMv;
  n0 = (lin % NY) * 128;
}

// ---------------- prep kernels ----------------
__global__ void k_zero4k(float* p) {
  p[blockIdx.x * 256 + threadIdx.x] = 0.f;
}

__global__ void k_castf2b(const float* __restrict__ s, bf16* __restrict__ d, int n) {
  int i = blockIdx.x * 256 + threadIdx.x;
  if (i < n) d[i] = __float2bfloat16(s[i]);
}

__global__ void k_copyf(const float* __restrict__ s, float* __restrict__ d, int n) {
  int i = blockIdx.x * 256 + threadIdx.x;
  if (i < n) d[i] = s[i];
}

// conv weight permute: OIHW fp32 -> [O][tap][I] bf16
__global__ void k_permconv(const float* __restrict__ w, bf16* __restrict__ o, int I) {
  int idx = blockIdx.x * 256 + threadIdx.x;
  int tot = 256 * 9 * I;
  if (idx >= tot) return;
  int i   = idx % I;
  int rem = idx / I;
  int tap = rem % 9;
  int oc  = rem / 9;
  o[idx] = __float2bfloat16(w[(oc * I + i) * 9 + tap]);
}

// NCHW fp32 -> NHWC bf16
__global__ void k_tohwc(const float* __restrict__ src, bf16* __restrict__ dst, int C) {
  int bh = blockIdx.x;
  int w0 = blockIdx.y * 32;
  int c0 = blockIdx.z * 32;
  int b = bh / Himg, h = bh % Himg;
  __shared__ float tile[32][33];
  int tid = threadIdx.x;
  int x = tid & 31, y = tid >> 5;
  const float* sp = src + (size_t)b * C * HWimg + (size_t)h * Wimg;
#pragma unroll
  for (int p = 0; p < 4; ++p) {
    int cl = y + p * 8;
    tile[cl][x] = sp[(size_t)(c0 + cl) * HWimg + w0 + x];
  }
  __syncthreads();
#pragma unroll
  for (int p = 0; p < 4; ++p) {
    int wl = y + p * 8;
    dst[((size_t)bh * Wimg + w0 + wl) * C + c0 + x] = __float2bfloat16(tile[x][wl]);
  }
}

// ================= 8-phase 256x256 GEMM / implicit conv (CIN=256) =================
template <int TAPS, int EPI>
__global__ void __launch_bounds__(512, 1)
k_gemm8(const bf16* __restrict__ Ain, const bf16* __restrict__ BT,
        const float* __restrict__ bias,
        bf16* __restrict__ outb, int ldo, float* __restrict__ outf,
        const bf16* __restrict__ ident,
        const bf16* __restrict__ zp)
{
  constexpr int KTOT = TAPS * 256;
  const int t0 = remap_lin(blockIdx.x, gridDim.x) * 256;
  const int tid  = threadIdx.x;
  const int wave = tid >> 6, lane = tid & 63;
  const int wr = wave >> 2, wc = wave & 3;
  const int fr = lane & 15, fq = lane >> 4;

  __shared__ __attribute__((aligned(16))) char arena[132608];
  bf16* A0k0 = (bf16*)(arena);
  bf16* A0k1 = (bf16*)(arena + 16384);
  bf16* A1k0 = (bf16*)(arena + 32768);
  bf16* A1k1 = (bf16*)(arena + 49152);
  bf16* B0k0 = (bf16*)(arena + 65536);
  bf16* B0k1 = (bf16*)(arena + 81920);
  bf16* B1k0 = (bf16*)(arena + 98304);
  bf16* B1k1 = (bf16*)(arena + 114688);

  f32x4 acc[8][4] = {};
  s16x8 bfr[4];

  const int slot8 = (fq ^ ((fr >> 1) & 3)) * 8;
  const int aoff  = (wr * 128 + fr) * 32 + slot8;
  const int boff  = (wc * 64 + fr) * 32 + slot8;
  const int ldsl  = (tid & 3) * 8;
  const int scol  = ((tid & 3) ^ ((tid >> 3) & 3)) * 8;
  const int srow  = tid >> 2;

  const bf16* Bb0 = BT + (size_t)srow * KTOT + scol;
  const bf16* Bb1 = BT + (size_t)(128 + srow) * KTOT + scol;
  const bf16* Aa0 = Ain + (size_t)(t0 + srow) * 256 + scol;
  const bf16* Aa1 = Ain + (size_t)(t0 + 128 + srow) * 256 + scol;
  const bf16 *a0c = Aa0, *a1c = Aa1, *a0n = Aa0, *a1n = Aa1;
  const int hU = (t0 >> 8) & 255;

  auto mkbase = [&](int tap, const bf16*& o0, const bf16*& o1) {
    const int dy = tap / 3 - 1, dx = tap % 3 - 1;
    const bool rowok = ((unsigned)(hU + dy)) < 256u;
    const long gb = (long)t0 + dy * Wimg + dx;
    o0 = (rowok && (unsigned)(srow + dx) < 256u)
             ? Ain + (gb + srow) * 256 + scol : zp + scol;
    o1 = (rowok && (unsigned)(128 + srow + dx) < 256u)
             ? Ain + (gb + 128 + srow) * 256 + scol : zp + scol;
  };

#define STA8(DST, P0, P1, CE) do {                                              \
    gld16(DST + srow * 32 + ldsl, (P0) + (CE));                                 \
    gld16(DST + (128 + srow) * 32 + ldsl, (P1) + (CE));                         \
  } while (0)
#define STB8(DST, KE) do {                                                      \
    gld16(DST + srow * 32 + ldsl, Bb0 + (KE));                                  \
    gld16(DST + (128 + srow) * 32 + ldsl, Bb1 + (KE));                          \
  } while (0)

#define NVMs
#define VM4 asm volatile("s_waitcnt vmcnt(4)" ::: "memory")
#define VM0 asm volatile("s_waitcnt vmcnt(0)" ::: "memory")

#define PHO(RA, RB, MH, READB, ...) do {                                         \
    s16x8 af_[4];                                                                \
    _Pragma("unroll") for (int q_ = 0; q_ < 4; ++q_)                             \
      af_[q_] = *(const s16x8*)((RA) + aoff + ((MH) * 4 + q_) * 512);            \
    if (READB) {                                                                 \
      _Pragma("unroll") for (int n_ = 0; n_ < 4; ++n_)                           \
        bfr[n_] = *(const s16x8*)((RB) + boff + n_ * 512);                       \
    }                                                                            \
    __VA_ARGS__;                                                                 \
    asm volatile("s_waitcnt lgkmcnt(0)" ::: "memory");                           \
    __builtin_amdgcn_sched_barrier(0);                                           \
    __builtin_amdgcn_s_setprio(1);                                               \
    _Pragma("unroll") for (int q_ = 0; q_ < 4; ++q_)                             \
      _Pragma("unroll") for (int n_ = 0; n_ < 4; ++n_)                           \
        acc[(MH) * 4 + q_][n_] = __builtin_amdgcn_mfma_f32_16x16x32_bf16(        \
            af_[q_], bfr[n_], acc[(MH) * 4 + q_][n_], 0, 0, 0);                  \
    __builtin_amdgcn_s_setprio(0);                                               \
  } while (0)

#define PHE(RA, RB, MH, READB, VMSTMT, ...) do {                                 \
    s16x8 af_[4];                                                                \
    _Pragma("unroll") for (int q_ = 0; q_ < 4; ++q_)                             \
      af_[q_] = *(const s16x8*)((RA) + aoff + ((MH) * 4 + q_) * 512);            \
    if (READB) {                                                                 \
      _Pragma("unroll") for (int n_ = 0; n_ < 4; ++n_)                           \
        bfr[n_] = *(const s16x8*)((RB) + boff + n_ * 512);                       \
    }                                                                            \
    __VA_ARGS__;                                                                 \
    VMSTMT;                                                                      \
    __builtin_amdgcn_sched_barrier(0);                                           \
    __builtin_amdgcn_s_barrier();                                                \
    asm volatile("s_waitcnt lgkmcnt(0)" ::: "memory");                           \
    __builtin_amdgcn_sched_barrier(0);                                           \
    __builtin_amdgcn_s_setprio(1);                                               \
    _Pragma("unroll") for (int q_ = 0; q_ < 4; ++q_)                             \
      _Pragma("unroll") for (int n_ = 0; n_ < 4; ++n_)                           \
        acc[(MH) * 4 + q_][n_] = __builtin_amdgcn_mfma_f32_16x16x32_bf16(        \
            af_[q_], bfr[n_], acc[(MH) * 4 + q_][n_], 0, 0, 0);                  \
    __builtin_amdgcn_s_setprio(0);                                               \
  } while (0)

  if constexpr (TAPS == 9) {
    mkbase(0, a0c, a1c);
    mkbase(1, a0n, a1n);
    STA8(A0k0, a0c, a1c, 0);  STB8(B0k0, 0);
    STA8(A0k1, a0c, a1c, 32); STB8(B0k1, 32);
    VM4;
    __builtin_amdgcn_s_barrier();
#pragma unroll 1
    for (int tap = 0; tap < 8; ++tap) {
      PHO(A0k0, B0k0, 0, 1, STA8(A1k0, a0c, a1c, 64));
      PHE(A0k0, B0k0, 1, 0, VM4, STB8(B1k0, 64));
      PHO(A0k1, B0k1, 0, 1, STA8(A1k1, a0c, a1c, 96));
      PHE(A0k1, B0k1, 1, 0, VM4, STB8(B1k1, 96));
      PHO(A1k0, B1k0, 0, 1, STA8(A0k0, a0c, a1c, 128));
      PHE(A1k0, B1k0, 1, 0, VM4, STB8(B0k0, 128));
      PHO(A1k1, B1k1, 0, 1, STA8(A0k1, a0c, a1c, 160));
      PHE(A1k1, B1k1, 1, 0, VM4, STB8(B0k1, 160));
      PHO(A0k0, B0k0, 0, 1, STA8(A1k0, a0c, a1c, 192));
      PHE(A0k0, B0k0, 1, 0, VM4, STB8(B1k0, 192));
      PHO(A0k1, B0k1, 0, 1, STA8(A1k1, a0c, a1c, 224));
      PHE(A0k1, B0k1, 1, 0, VM4, STB8(B1k1, 224));
      PHO(A1k0, B1k0, 0, 1, STA8(A0k0, a0n, a1n, 0));
      PHE(A1k0, B1k0, 1, 0, VM4, STB8(B0k0, 256));
      PHO(A1k1, B1k1, 0, 1, STA8(A0k1, a0n, a1n, 32));
      PHE(A1k1, B1k1, 1, 0, VM4, STB8(B0k1, 288));
      a0c = a0n; a1c = a1n;
      if (tap + 2 < 9) mkbase(tap + 2, a0n, a1n);
      Bb0 += 256; Bb1 += 256;
    }
    PHO(A0k0, B0k0, 0, 1, STA8(A1k0, a0c, a1c, 64));
    PHE(A0k0, B0k0, 1, 0, VM4, STB8(B1k0, 64));
    PHO(A0k1, B0k1, 0, 1, STA8(A1k1, a0c, a1c, 96));
    PHE(A0k1, B0k1, 1, 0, VM4, STB8(B1k1, 96));
    PHO(A1k0, B1k0, 0, 1, STA8(A0k0, a0c, a1c, 128));
    PHE(A1k0, B1k0, 1, 0, VM4, STB8(B0k0, 128));
    PHO(A1k1, B1k1, 0, 1, STA8(A0k1, a0c, a1c, 160));
    PHE(A1k1, B1k1, 1, 0, VM4, STB8(B0k1, 160));
    PHO(A0k0, B0k0, 0, 1, STA8(A1k0, a0c, a1c, 192));
    PHE(A0k0, B0k0, 1, 0, VM4, STB8(B1k0, 192));
    PHO(A0k1, B0k1, 0, 1, STA8(A1k1, a0c, a1c, 224));
    PHE(A0k1, B0k1, 1, 0, VM4, STB8(B1k1, 224));
    PHO(A1k0, B1k0, 0, 1, );
    PHE(A1k0, B1k0, 1, 0, VM0, );
    PHO(A1k1, B1k1, 0, 1, );
    PHE(A1k1, B1k1, 1, 0, NVMs, );
  } else {
    STA8(A0k0, Aa0, Aa1, 0);  STB8(B0k0, 0);
    STA8(A0k1, Aa0, Aa1, 32); STB8(B0k1, 32);
    VM4;
    __builtin_amdgcn_s_barrier();
    PHO(A0k0, B0k0, 0, 1, STA8(A1k0, Aa0, Aa1, 64));
    PHE(A0k0, B0k0, 1, 0, VM4, STB8(B1k0, 64));
    PHO(A0k1, B0k1, 0, 1, STA8(A1k1, Aa0, Aa1, 96));
    PHE(A0k1, B0k1, 1, 0, VM4, STB8(B1k1, 96));
    PHO(A1k0, B1k0, 0, 1, STA8(A0k0, Aa0, Aa1, 128));
    PHE(A1k0, B1k0, 1, 0, VM4, STB8(B0k0, 128));
    PHO(A1k1, B1k1, 0, 1, STA8(A0k1, Aa0, Aa1, 160));
    PHE(A1k1, B1k1, 1, 0, VM4, STB8(B0k1, 160));
    PHO(A0k0, B0k0, 0, 1, STA8(A1k0, Aa0, Aa1, 192));
    PHE(A0k0, B0k0, 1, 0, VM4, STB8(B1k0, 192));
    PHO(A0k1, B0k1, 0, 1, STA8(A1k1, Aa0, Aa1, 224));
    PHE(A0k1, B0k1, 1, 0, VM4, STB8(B1k1, 224));
    PHO(A1k0, B1k0, 0, 1, );
    PHE(A1k0, B1k0, 1, 0, VM0, );
    PHO(A1k1, B1k1, 0, 1, );
    PHE(A1k1, B1k1, 1, 0, NVMs, );
  }
#undef PHO
#undef PHE
#undef STA8
#undef STB8
#undef NVMs
#undef VM4
#undef VM0

  if (EPI == 2) {
    float* TR = (float*)arena;
    const int bN = t0 >> 16, hN = (t0 >> 8) & 255;
#pragma unroll 1
    for (int chunk = 0; chunk < 2; ++chunk) {
      __builtin_amdgcn_s_barrier();
      if ((wc >> 1) == chunk) {
#pragma unroll
        for (int m = 0; m < 8; ++m)
#pragma unroll
          for (int n = 0; n < 4; ++n) {
            const int col = wc * 64 + n * 16 + fr;
            const int cl  = (wc & 1) * 64 + n * 16 + fr;
            const float bb = bias[col];
#pragma unroll
            for (int j = 0; j < 4; ++j) {
              const int row = wr * 128 + m * 16 + fq * 4 + j;
              const size_t t = (size_t)t0 + row;
              TR[cl * 259 + row] = acc[m][n][j] + bb +
                                   __bfloat162float(ident[t * 256 + col]);
            }
          }
      }
      __builtin_amdgcn_s_barrier();
      {
        const int cl = tid >> 2, wo = (tid & 3) * 4;
        const int c = chunk * 128 + cl;
        float* dp = outf + (((size_t)bN * 256 + c) * 256 + hN) * 256;
#pragma unroll
        for (int q = 0; q < 16; ++q)
          *(f32x4*)(dp + wo + q * 16) = *(const f32x4*)&TR[cl * 259 + wo + q * 16];
      }
    }
    return;
  }

#pragma unroll
  for (int m = 0; m < 8; ++m) {
#pragma unroll
    for (int n = 0; n < 4; ++n) {
      const int col = wc * 64 + n * 16 + fr;
#pragma unroll
      for (int j = 0; j < 4; ++j) {
        const int row = wr * 128 + m * 16 + fq * 4 + j;
        const size_t t = (size_t)t0 + row;
        outb[t * ldo + col] = __float2bfloat16(acc[m][n][j] + bias[col]);
      }
    }
  }
}

// ---------------- 3-buffer GEMM (kept for cfeat conv, CIN=32) ----------------
template <int CIN, int TAPS, int EPI>
__global__ void __launch_bounds__(256, 2)
k_gemm(const bf16* __restrict__ Ain, const bf16* __restrict__ BT,
       const float* __restrict__ bias,
       bf16* __restrict__ outb, int ldo,
       const bf16* __restrict__ ident,
       const bf16* __restrict__ zp, int NY)
{
  constexpr int KTOT = TAPS * CIN;
  constexpr int NK = KTOT / 32;
  int t0, n0;
  remap_tile(blockIdx.x, gridDim.x, NY, 256, t0, n0);
  const int tid = threadIdx.x;
  const int wave = tid >> 6, lane = tid & 63;
  const int seg = lane & 3;
  const int rr  = lane >> 2;

  __shared__ bf16 sA0[256 * 32];
  __shared__ bf16 sA1[256 * 32];
  __shared__ bf16 sA2[256 * 32];
  __shared__ bf16 sB0[128 * 32];
  __shared__ bf16 sB1[128 * 32];
  __shared__ bf16 sB2[128 * 32];

  f32x4 acc[8][4] = {};

  const int wr = wave >> 1, wc = wave & 1;
  const int fr = lane & 15, fq = lane >> 4;
  const int sseg = (seg ^ ((rr >> 1) & 3)) * 8;
  const int slot = (fq ^ ((fr >> 1) & 3)) * 8;

#define STAGE(WA, WB, KSV) do {                                                 \
    const int k0_ = (KSV) * 32;                                                 \
    const int tap_ = k0_ / CIN;                                                 \
    const int c0_ = k0_ - tap_ * CIN;                                           \
    const int dy_ = tap_ / 3 - 1, dx_ = tap_ % 3 - 1;                           \
    _Pragma("unroll") for (int i_ = 0; i_ < 4; ++i_) {                          \
      const int g_ = i_ * 4 + wave;                                             \
      const int t_ = t0 + g_ * 16 + rr;                                         \
      const bf16* src_;                                                         \
      if (TAPS == 1) {                                                          \
        src_ = Ain + (size_t)t_ * CIN + k0_ + sseg;                             \
      } else {                                                                  \
        const int hh_ = ((t_ >> 8) & 255) + dy_, ww_ = (t_ & 255) + dx_;        \
        const bool v_ = ((unsigned)hh_ < 256u) && ((unsigned)ww_ < 256u);       \
        const long gi_ = (long)t_ + dy_ * Wimg + dx_;                           \
        src_ = v_ ? (Ain + gi_ * CIN + c0_ + sseg) : (zp + sseg);               \
      }                                                                         \
      gld16(WA + g_ * 16 * 32, src_);                                           \
    }                                                                           \
    _Pragma("unroll") for (int i_ = 0; i_ < 2; ++i_) {                          \
      const int g_ = i_ * 4 + wave;                                             \
      gld16(WB + g_ * 16 * 32,                                                  \
            BT + (size_t)(n0 + g_ * 16 + rr) * KTOT + k0_ + sseg);              \
    }                                                                           \
  } while (0)

#define GSTEP(RA, RB, WA, WB, KSV, LASTF) do {                                  \
    if (LASTF) { asm volatile("s_waitcnt vmcnt(0)" ::: "memory"); }             \
    else       { asm volatile("s_waitcnt vmcnt(6)" ::: "memory"); }             \
    __builtin_amdgcn_s_barrier();                                               \
    s16x8 af_[8], bf_[4];                                                       \
    _Pragma("unroll") for (int m_ = 0; m_ < 8; ++m_)                            \
      af_[m_] = *(const s16x8*)(RA + (wr * 128 + m_ * 16 + fr) * 32 + slot);    \
    _Pragma("unroll") for (int n_ = 0; n_ < 4; ++n_)                            \
      bf_[n_] = *(const s16x8*)(RB + (wc * 64 + n_ * 16 + fr) * 32 + slot);     \
    if ((KSV) + 2 < NK) STAGE(WA, WB, (KSV) + 2);                               \
    __builtin_amdgcn_s_setprio(1);                                              \
    _Pragma("unroll") for (int m_ = 0; m_ < 8; ++m_)                            \
      _Pragma("unroll") for (int n_ = 0; n_ < 4; ++n_)                          \
        acc[m_][n_] = __builtin_amdgcn_mfma_f32_16x16x32_bf16(af_[m_], bf_[n_], acc[m_][n_], 0, 0, 0); \
    __builtin_amdgcn_s_setprio(0);                                              \
  } while (0)

  STAGE(sA0, sB0, 0);
  STAGE(sA1, sB1, 1);

  constexpr int NMAIN = ((NK - 1) / 3) * 3;
  int ks = 0;
#pragma unroll 1
  for (; ks < NMAIN; ks += 3) {
    GSTEP(sA0, sB0, sA2, sB2, ks,     false);
    GSTEP(sA1, sB1, sA0, sB0, ks + 1, false);
    GSTEP(sA2, sB2, sA1, sB1, ks + 2, false);
  }
  constexpr int TREM = NK - NMAIN;
  if constexpr (TREM == 3) {
    GSTEP(sA0, sB0, sA2, sB2, NMAIN,     false);
    GSTEP(sA1, sB1, sA0, sB0, NMAIN + 1, false);
    GSTEP(sA2, sB2, sA1, sB1, NMAIN + 2, true);
  } else if constexpr (TREM == 2) {
    GSTEP(sA0, sB0, sA2, sB2, NMAIN,     false);
    GSTEP(sA1, sB1, sA0, sB0, NMAIN + 1, true);
  } else {
    GSTEP(sA0, sB0, sA2, sB2, NMAIN,     true);
  }
#undef GSTEP
#undef STAGE

#pragma unroll
  for (int m = 0; m < 8; ++m) {
#pragma unroll
    for (int n = 0; n < 4; ++n) {
      const int col = n0 + wc * 64 + n * 16 + fr;
#pragma unroll
      for (int j = 0; j < 4; ++j) {
        const int row = wr * 128 + m * 16 + fq * 4 + j;
        const size_t t = (size_t)t0 + row;
        float v = acc[m][n][j] + bias[col];
        if (EPI == 0) {
          outb[t * ldo + col] = __float2bfloat16(v);
        } else {
          v += __bfloat162float(ident[t * 256 + col]);
          outb[t * 256 + col] = __float2bfloat16(v);
        }
      }
    }
  }
}

// ---------------- gated dual GEMM (static triple-buffer pipeline + swizzle) ----------------
__global__ void __launch_bounds__(256, 3)
k_gemm_qkv(const bf16* __restrict__ Am, const bf16* __restrict__ Af,
           const bf16* __restrict__ Bm, const bf16* __restrict__ Bf,
           const float* __restrict__ bm, const float* __restrict__ bfi,
           bf16* __restrict__ out)
{
  int t0, n0;
  remap_tile(blockIdx.x, gridDim.x, 4, 128, t0, n0);
  const int tid = threadIdx.x;
  const int wave = tid >> 6, lane = tid & 63;
  const int seg = lane & 3;
  const int rr  = lane >> 2;

  __shared__ bf16 sA0[128 * 32];
  __shared__ bf16 sA1[128 * 32];
  __shared__ bf16 sA2[128 * 32];
  __shared__ bf16 sB0[128 * 32];
  __shared__ bf16 sB1[128 * 32];
  __shared__ bf16 sB2[128 * 32];

  f32x4 accm[4][4] = {};
  f32x4 accf[4][4] = {};

  const int wr = wave >> 1, wc = wave & 1;
  const int fr = lane & 15, fq = lane >> 4;
  const int sseg = (seg ^ ((rr >> 1) & 3)) * 8;
  const int slot = (fq ^ ((fr >> 1) & 3)) * 8;

#define STAGEQ(WA, WB, SV) do {                                                 \
    const int k0_ = ((SV) >> 1) * 32;                                           \
    const bf16* A_ = ((SV) & 1) ? Af : Am;                                      \
    const bf16* B_ = ((SV) & 1) ? Bf : Bm;                                      \
    _Pragma("unroll") for (int i_ = 0; i_ < 2; ++i_) {                          \
      const int r_ = wave * 32 + i_ * 16 + rr;                                  \
      gld16(WA + (wave * 32 + i_ * 16) * 32, A_ + (size_t)(t0 + r_) * 256 + k0_ + sseg); \
      gld16(WB + (wave * 32 + i_ * 16) * 32, B_ + (size_t)(n0 + r_) * 256 + k0_ + sseg); \
    }                                                                           \
  } while (0)

#define QSTEP(RA, RB, WA, WB, SV, LASTF) do {                                   \
    if (LASTF) { asm volatile("s_waitcnt vmcnt(0)" ::: "memory"); }             \
    else       { asm volatile("s_waitcnt vmcnt(4)" ::: "memory"); }             \
    __builtin_amdgcn_s_barrier();                                               \
    s16x8 af_[4], bf_[4];                                                       \
    _Pragma("unroll") for (int m_ = 0; m_ < 4; ++m_)                            \
      af_[m_] = *(const s16x8*)(RA + (wr * 64 + m_ * 16 + fr) * 32 + slot);     \
    _Pragma("unroll") for (int n_ = 0; n_ < 4; ++n_)                            \
      bf_[n_] = *(const s16x8*)(RB + (wc * 64 + n_ * 16 + fr) * 32 + slot);     \
    if ((SV) + 2 < 16) STAGEQ(WA, WB, (SV) + 2);                                \
    __builtin_amdgcn_s_setprio(1);                                              \
    if ((SV) & 1) {                                                             \
      _Pragma("unroll") for (int m_ = 0; m_ < 4; ++m_)                          \
        _Pragma("unroll") for (int n_ = 0; n_ < 4; ++n_)                        \
          accf[m_][n_] = __builtin_amdgcn_mfma_f32_16x16x32_bf16(af_[m_], bf_[n_], accf[m_][n_], 0, 0, 0); \
    } else {                                                                    \
      _Pragma("unroll") for (int m_ = 0; m_ < 4; ++m_)                          \
        _Pragma("unroll") for (int n_ = 0; n_ < 4; ++n_)                        \
          accm[m_][n_] = __builtin_amdgcn_mfma_f32_16x16x32_bf16(af_[m_], bf_[n_], accm[m_][n_], 0, 0, 0); \
    }                                                                           \
    __builtin_amdgcn_s_setprio(0);                                              \
  } while (0)

  STAGEQ(sA0, sB0, 0);
  STAGEQ(sA1, sB1, 1);

  int s = 0;
#pragma unroll 1
  for (; s < 15; s += 3) {
    QSTEP(sA0, sB0, sA2, sB2, s,     false);
    QSTEP(sA1, sB1, sA0, sB0, s + 1, false);
    QSTEP(sA2, sB2, sA1, sB1, s + 2, false);
  }
  QSTEP(sA0, sB0, sA2, sB2, 15, true);
#undef QSTEP
#undef STAGEQ

#pragma unroll
  for (int m = 0; m < 4; ++m) {
#pragma unroll
    for (int n = 0; n < 4; ++n) {
      const int col = n0 + wc * 64 + n * 16 + fr;
#pragma unroll
      for (int j = 0; j < 4; ++j) {
        const int row = wr * 64 + m * 16 + fq * 4 + j;
        const size_t t = (size_t)t0 + row;
        float v = accm[m][n][j] + bm[col];
        const float g = accf[m][n][j] + bfi[col];
        v *= 1.f / (1.f + __expf(-g));
        out[t * 768 + col] = __float2bfloat16(v);
      }
    }
  }
}

// ---------------- MFMA window attention (coalesced LDS staging) ----------------
__global__ void __launch_bounds__(256, 4)
k_attn_mfma(const bf16* __restrict__ qkv, bf16* __restrict__ out) {
  __shared__ short smem[4 * 7424];   // 14848 B per wave
  const int tid = threadIdx.x;
  const int wave = tid >> 6, lane = tid & 63;
  const int fr = lane & 15, fq = lane >> 4;
  const int wi = blockIdx.x >> 1;
  const int head = (blockIdx.x & 1) * 4 + wave;
  const int b = wi >> 10, rem = wi & 1023, wh = rem >> 5, ww = rem & 31;
  const size_t tbase = (size_t)b * HWimg + (size_t)(wh * 8) * Wimg + ww * 8;

  short* Qs = smem + wave * 7424;     // [64][40]
  short* Ks = Qs + 2560;              // [64][40]
  short* VT = Qs + 5120;              // [32][72]
  short* P  = Qs;                     // [64][72] alias
  short* Ol = Qs;                     // [64][40] alias

  auto tok = [&](int i) -> size_t {
    return tbase + (size_t)(i >> 3) * Wimg + (i & 7);
  };

  {
    const bf16* tb = qkv + tok(lane) * 768 + head * 32;
#pragma unroll
    for (int c = 0; c < 4; ++c) {
      s16x8 qv = *(const s16x8*)(tb + c * 8);
      s16x8 kv = *(const s16x8*)(tb + 256 + c * 8);
      s16x8 vv = *(const s16x8*)(tb + 512 + c * 8);
      *(s16x8*)(Qs + lane * 40 + c * 8) = qv;
      *(s16x8*)(Ks + lane * 40 + c * 8) = kv;
#pragma unroll
      for (int e = 0; e < 8; ++e) VT[(c * 8 + e) * 72 + lane] = vv[e];
    }
  }

  s16x8 kf[4], qf[4];
#pragma unroll
  for (int m = 0; m < 4; ++m)
    kf[m] = *(const s16x8*)(Ks + (fr + 16 * m) * 40 + fq * 8);
#pragma unroll
  for (int n = 0; n < 4; ++n)
    qf[n] = *(const s16x8*)(Qs + (fr + 16 * n) * 40 + fq * 8);

  f32x4 st[4][4] = {};
#pragma unroll
  for (int m = 0; m < 4; ++m)
#pragma unroll
    for (int n = 0; n < 4; ++n)
      st[m][n] = __builtin_amdgcn_mfma_f32_16x16x32_bf16(kf[m], qf[n], st[m][n], 0, 0, 0);

  const float scale = 0.17677669529663688f;  // 1/sqrt(32)
  float invs[4];
#pragma unroll
  for (int n = 0; n < 4; ++n) {
    float mx = -1e30f;
#pragma unroll
    for (int m = 0; m < 4; ++m)
#pragma unroll
      for (int j = 0; j < 4; ++j) mx = fmaxf(mx, st[m][n][j]);
    mx = fmaxf(mx, __shfl_xor(mx, 16));
    mx = fmaxf(mx, __shfl_xor(mx, 32));
    float sum = 0.f;
#pragma unroll
    for (int m = 0; m < 4; ++m) {
      s16x4 pk;
#pragma unroll
      for (int j = 0; j < 4; ++j) {
        float e = __expf((st[m][n][j] - mx) * scale);
        sum += e;
        pk[j] = (short)f2u(e);
      }
      *(s16x4*)(P + (fr + 16 * n) * 72 + 16 * m + 4 * fq) = pk;
    }
    sum += __shfl_xor(sum, 16);
    sum += __shfl_xor(sum, 32);
    invs[n] = 1.f / sum;
  }

  f32x4 oc[4][2] = {};
#pragma unroll
  for (int ks = 0; ks < 2; ++ks) {
    s16x8 pf[4], vf[2];
#pragma unroll
    for (int m = 0; m < 4; ++m)
      pf[m] = *(const s16x8*)(P + (fr + 16 * m) * 72 + ks * 32 + fq * 8);
#pragma unroll
    for (int n = 0; n < 2; ++n)
      vf[n] = *(const s16x8*)(VT + (fr + 16 * n) * 72 + ks * 32 + fq * 8);
#pragma unroll
    for (int m = 0; m < 4; ++m)
#pragma unroll
      for (int n = 0; n < 2; ++n)
        oc[m][n] = __builtin_amdgcn_mfma_f32_16x16x32_bf16(pf[m], vf[n], oc[m][n], 0, 0, 0);
  }

#pragma unroll
  for (int m = 0; m < 4; ++m)
#pragma unroll
    for (int j = 0; j < 4; ++j) {
      const float inv = __shfl(invs[m], 4 * fq + j);
      const int q = 16 * m + 4 * fq + j;
#pragma unroll
      for (int n = 0; n < 2; ++n)
        Ol[q * 40 + fr + 16 * n] = (short)f2u(oc[m][n][j] * inv);
    }
  {
    bf16* op = out + tok(lane) * 256 + head * 32;
#pragma unroll
    for (int c = 0; c < 4; ++c)
      *(s16x8*)(op + c * 8) = *(const s16x8*)(Ol + lane * 40 + c * 8);
  }
}

// ---------------- host ----------------
extern "C" void kernel_launch(void* const* d_in, const int* in_sizes, int n_in,
                              void* d_out, int out_size, void* d_ws, size_t ws_size,
                              hipStream_t stream) {
  const float* xmap    = (const float*)d_in[0];
  const float* xfeat   = (const float*)d_in[1];
  const float* cmap_w  = (const float*)d_in[2];
  const float* cmap_b  = (const float*)d_in[3];
  const float* cfeat_w = (const float*)d_in[4];
  const float* cfeat_b = (const float*)d_in[5];
  const float* qxmap_w = (const float*)d_in[6];
  const float* qxmap_b = (const float*)d_in[7];
  const float* kxmap_w = (const float*)d_in[8];
  const float* kxmap_b = (const float*)d_in[9];
  const float* vxmap_w = (const float*)d_in[10];
  const float* vxmap_b = (const float*)d_in[11];
  const float* qxfeat_w = (const float*)d_in[12];
  const float* qxfeat_b = (const float*)d_in[13];
  const float* kxfeat_w = (const float*)d_in[14];
  const float* kxfeat_b = (const float*)d_in[15];
  const float* proj_w  = (const float*)d_in[16];
  const float* proj_b  = (const float*)d_in[17];
  const float* cout_w  = (const float*)d_in[18];
  const float* cout_b  = (const float*)d_in[19];

  uint8_t* ws = (uint8_t*)d_ws;
  size_t off = 0;
  auto alloc = [&](size_t bytes) -> void* {
    void* p = ws + off;
    off += (bytes + 255) & ~(size_t)255;
    return p;
  };
  float* zp       = (float*)alloc(4096);
  bf16* cmap_wT   = (bf16*)alloc((size_t)2304 * 256 * 2);
  bf16* cout_wT   = (bf16*)alloc((size_t)2304 * 256 * 2);
  bf16* cfeat_wT  = (bf16*)alloc((size_t)288 * 256 * 2);
  bf16* lin_qkv_wT= (bf16*)alloc((size_t)768 * 256 * 2);
  bf16* lin_f_wT  = (bf16*)alloc((size_t)512 * 256 * 2);
  bf16* proj_wT   = (bf16*)alloc((size_t)256 * 256 * 2);
  float* bias_qkv = (float*)alloc(768 * 4);
  float* bias_f   = (float*)alloc(512 * 4);
  bf16* xm_nhwc   = (bf16*)alloc((size_t)Ttok * 256 * 2);
  bf16* xf_nhwc   = (bf16*)alloc((size_t)Ttok * 32 * 2);
  bf16* xc        = (bf16*)alloc((size_t)Ttok * 256 * 2);
  bf16* fc        = (bf16*)alloc((size_t)Ttok * 256 * 2);
  bf16* qkv       = (bf16*)alloc((size_t)Ttok * 768 * 2);
  bf16* attn_out  = xm_nhwc;          // reuse (dead after cmap conv)
  bf16* proj_out  = fc;               // reuse (dead after qkv GEMMs)
  bf16* zpb = (bf16*)zp;

  k_zero4k<<<4, 256, 0, stream>>>(zp);
  k_permconv<<<(256 * 9 * 256 + 255) / 256, 256, 0, stream>>>(cmap_w, cmap_wT, 256);
  k_permconv<<<(256 * 9 * 256 + 255) / 256, 256, 0, stream>>>(cout_w, cout_wT, 256);
  k_permconv<<<(256 * 9 * 32 + 255) / 256, 256, 0, stream>>>(cfeat_w, cfeat_wT, 32);
  k_castf2b<<<256, 256, 0, stream>>>(qxmap_w, lin_qkv_wT, 65536);
  k_castf2b<<<256, 256, 0, stream>>>(kxmap_w, lin_qkv_wT + 65536, 65536);
  k_castf2b<<<256, 256, 0, stream>>>(vxmap_w, lin_qkv_wT + 131072, 65536);
  k_castf2b<<<256, 256, 0, stream>>>(qxfeat_w, lin_f_wT, 65536);
  k_castf2b<<<256, 256, 0, stream>>>(kxfeat_w, lin_f_wT + 65536, 65536);
  k_castf2b<<<256, 256, 0, stream>>>(proj_w, proj_wT, 65536);
  k_copyf<<<1, 256, 0, stream>>>(qxmap_b, bias_qkv, 256);
  k_copyf<<<1, 256, 0, stream>>>(kxmap_b, bias_qkv + 256, 256);
  k_copyf<<<1, 256, 0, stream>>>(vxmap_b, bias_qkv + 512, 256);
  k_copyf<<<1, 256, 0, stream>>>(qxfeat_b, bias_f, 256);
  k_copyf<<<1, 256, 0, stream>>>(kxfeat_b, bias_f + 256, 256);

  k_tohwc<<<dim3(Bimg * Himg, Wimg / 32, 256 / 32), 256, 0, stream>>>(xmap, xm_nhwc, 256);
  k_tohwc<<<dim3(Bimg * Himg, Wimg / 32, 1), 256, 0, stream>>>(xfeat, xf_nhwc, 32);

  const int NB = Ttok / 256;   // 1024 blocks for 8-phase kernels (BN=256, NY=1)
  // conv cmap -> xc
  k_gemm8<9, 0><<<dim3(NB), dim3(512), 0, stream>>>(
      xm_nhwc, cmap_wT, cmap_b, xc, 256, nullptr, nullptr, zpb);
  // conv cfeat -> fc (CIN=32, 3-buffer structure)
  k_gemm<32, 9, 0><<<dim3(NB * 2), dim3(256), 0, stream>>>(
      xf_nhwc, cfeat_wT, cfeat_b, fc, 256, nullptr, zpb, 2);
  // v-linear -> qkv[:,512:768]
  k_gemm8<1, 0><<<dim3(NB), dim3(512), 0, stream>>>(
      xc, lin_qkv_wT + 131072, bias_qkv + 512, qkv + 512, 768, nullptr, nullptr, zpb);
  // gated q,k -> qkv[:,0:512] (fused dual GEMM)
  k_gemm_qkv<<<dim3((Ttok / 128) * 4), dim3(256), 0, stream>>>(
      xc, fc, lin_qkv_wT, lin_f_wT, bias_qkv, bias_f, qkv);
  // MFMA window attention
  k_attn_mfma<<<dim3(4096 * 2), dim3(256), 0, stream>>>(qkv, attn_out);
  // proj GEMM
  k_gemm8<1, 0><<<dim3(NB), dim3(512), 0, stream>>>(
      attn_out, proj_wT, proj_b, proj_out, 256, nullptr, nullptr, zpb);
  // conv cout + bias + identity -> d_out NCHW fp32 directly (fused transpose)
  k_gemm8<9, 2><<<dim3(NB), dim3(512), 0, stream>>>(
      proj_out, cout_wT, cout_b, nullptr, 0, (float*)d_out, xc, zpb);
}

// Round 16
// 1403.621 us; speedup vs baseline: 2.1991x; 2.1991x over previous
//
#include <hip/hip_runtime.h>
#include <hip/hip_bf16.h>
#include <cstdint>
#include <math.h>

using bf16 = __hip_bfloat16;
typedef __attribute__((ext_vector_type(4))) float f32x4;
typedef __attribute__((ext_vector_type(8))) short s16x8;
typedef __attribute__((ext_vector_type(4))) short s16x4;

#define AS3(p) ((__attribute__((address_space(3))) void *)(p))
#define AS1(p) ((const __attribute__((address_space(1))) void *)(p))

static constexpr int Himg = 256, Wimg = 256, Bimg = 4;
static constexpr int HWimg = Himg * Wimg;
static constexpr int Ttok = Bimg * HWimg;   // 262144 tokens

__device__ __forceinline__ void gld16(bf16* lds, const bf16* g) {
  __builtin_amdgcn_global_load_lds(AS1(g), AS3(lds), 16, 0, 0);
}

__device__ __forceinline__ unsigned short f2u(float f) {
  bf16 b = __float2bfloat16(f);
  unsigned short u; __builtin_memcpy(&u, &b, 2); return u;
}

// XCD-chunked remap (1D): hw round-robin (bid%8) -> contiguous logical chunks.
__device__ __forceinline__ int remap_lin(int bid, int total) {
  return (bid & 7) * (total >> 3) + (bid >> 3);
}
__device__ __forceinline__ void remap_tile(int bid, int total, int NY, int BMv, int& t0, int& n0) {
  int lin = remap_lin(bid, total);
  t0 = (lin / NY) * BMv;
  n0 = (lin % NY) * 128;
}

// ---------------- prep kernels ----------------
__global__ void k_zero4k(float* p) {
  p[blockIdx.x * 256 + threadIdx.x] = 0.f;
}

__global__ void k_castf2b(const float* __restrict__ s, bf16* __restrict__ d, int n) {
  int i = blockIdx.x * 256 + threadIdx.x;
  if (i < n) d[i] = __float2bfloat16(s[i]);
}

__global__ void k_copyf(const float* __restrict__ s, float* __restrict__ d, int n) {
  int i = blockIdx.x * 256 + threadIdx.x;
  if (i < n) d[i] = s[i];
}

// conv weight permute: OIHW fp32 -> [O][tap][I] bf16
__global__ void k_permconv(const float* __restrict__ w, bf16* __restrict__ o, int I) {
  int idx = blockIdx.x * 256 + threadIdx.x;
  int tot = 256 * 9 * I;
  if (idx >= tot) return;
  int i   = idx % I;
  int rem = idx / I;
  int tap = rem % 9;
  int oc  = rem / 9;
  o[idx] = __float2bfloat16(w[(oc * I + i) * 9 + tap]);
}

// NCHW fp32 -> NHWC bf16
__global__ void k_tohwc(const float* __restrict__ src, bf16* __restrict__ dst, int C) {
  int bh = blockIdx.x;
  int w0 = blockIdx.y * 32;
  int c0 = blockIdx.z * 32;
  int b = bh / Himg, h = bh % Himg;
  __shared__ float tile[32][33];
  int tid = threadIdx.x;
  int x = tid & 31, y = tid >> 5;
  const float* sp = src + (size_t)b * C * HWimg + (size_t)h * Wimg;
#pragma unroll
  for (int p = 0; p < 4; ++p) {
    int cl = y + p * 8;
    tile[cl][x] = sp[(size_t)(c0 + cl) * HWimg + w0 + x];
  }
  __syncthreads();
#pragma unroll
  for (int p = 0; p < 4; ++p) {
    int wl = y + p * 8;
    dst[((size_t)bh * Wimg + w0 + wl) * C + c0 + x] = __float2bfloat16(tile[x][wl]);
  }
}

// ================= 8-phase 256x256 GEMM / implicit conv (CIN=256) =================
template <int TAPS, int EPI>
__global__ void __launch_bounds__(512, 1)
k_gemm8(const bf16* __restrict__ Ain, const bf16* __restrict__ BT,
        const float* __restrict__ bias,
        bf16* __restrict__ outb, int ldo, float* __restrict__ outf,
        const bf16* __restrict__ ident,
        const bf16* __restrict__ zp)
{
  constexpr int KTOT = TAPS * 256;
  const int t0 = remap_lin(blockIdx.x, gridDim.x) * 256;
  const int tid  = threadIdx.x;
  const int wave = tid >> 6, lane = tid & 63;
  const int wr = wave >> 2, wc = wave & 3;
  const int fr = lane & 15, fq = lane >> 4;

  __shared__ __attribute__((aligned(16))) char arena[132608];
  bf16* A0k0 = (bf16*)(arena);
  bf16* A0k1 = (bf16*)(arena + 16384);
  bf16* A1k0 = (bf16*)(arena + 32768);
  bf16* A1k1 = (bf16*)(arena + 49152);
  bf16* B0k0 = (bf16*)(arena + 65536);
  bf16* B0k1 = (bf16*)(arena + 81920);
  bf16* B1k0 = (bf16*)(arena + 98304);
  bf16* B1k1 = (bf16*)(arena + 114688);

  f32x4 acc[8][4] = {};
  s16x8 bfr[4];

  const int slot8 = (fq ^ ((fr >> 1) & 3)) * 8;
  const int aoff  = (wr * 128 + fr) * 32 + slot8;
  const int boff  = (wc * 64 + fr) * 32 + slot8;
  const int ldsl  = (tid & 3) * 8;
  const int scol  = ((tid & 3) ^ ((tid >> 3) & 3)) * 8;
  const int srow  = tid >> 2;

  const bf16* Bb0 = BT + (size_t)srow * KTOT + scol;
  const bf16* Bb1 = BT + (size_t)(128 + srow) * KTOT + scol;
  const bf16* Aa0 = Ain + (size_t)(t0 + srow) * 256 + scol;
  const bf16* Aa1 = Ain + (size_t)(t0 + 128 + srow) * 256 + scol;
  const bf16 *a0c = Aa0, *a1c = Aa1, *a0n = Aa0, *a1n = Aa1;
  const int hU = (t0 >> 8) & 255;

  auto mkbase = [&](int tap, const bf16*& o0, const bf16*& o1) {
    const int dy = tap / 3 - 1, dx = tap % 3 - 1;
    const bool rowok = ((unsigned)(hU + dy)) < 256u;
    const long gb = (long)t0 + dy * Wimg + dx;
    o0 = (rowok && (unsigned)(srow + dx) < 256u)
             ? Ain + (gb + srow) * 256 + scol : zp + scol;
    o1 = (rowok && (unsigned)(128 + srow + dx) < 256u)
             ? Ain + (gb + 128 + srow) * 256 + scol : zp + scol;
  };

#define STA8(DST, P0, P1, CE) do {                                              \
    gld16(DST + srow * 32 + ldsl, (P0) + (CE));                                 \
    gld16(DST + (128 + srow) * 32 + ldsl, (P1) + (CE));                         \
  } while (0)
#define STB8(DST, KE) do {                                                      \
    gld16(DST + srow * 32 + ldsl, Bb0 + (KE));                                  \
    gld16(DST + (128 + srow) * 32 + ldsl, Bb1 + (KE));                          \
  } while (0)

#define NVMs
#define VM4 asm volatile("s_waitcnt vmcnt(4)" ::: "memory")
#define VM0 asm volatile("s_waitcnt vmcnt(0)" ::: "memory")

#define PHO(RA, RB, MH, READB, ...) do {                                         \
    s16x8 af_[4];                                                                \
    _Pragma("unroll") for (int q_ = 0; q_ < 4; ++q_)                             \
      af_[q_] = *(const s16x8*)((RA) + aoff + ((MH) * 4 + q_) * 512);            \
    if (READB) {                                                                 \
      _Pragma("unroll") for (int n_ = 0; n_ < 4; ++n_)                           \
        bfr[n_] = *(const s16x8*)((RB) + boff + n_ * 512);                       \
    }                                                                            \
    __VA_ARGS__;                                                                 \
    asm volatile("s_waitcnt lgkmcnt(0)" ::: "memory");                           \
    __builtin_amdgcn_sched_barrier(0);                                           \
    __builtin_amdgcn_s_setprio(1);                                               \
    _Pragma("unroll") for (int q_ = 0; q_ < 4; ++q_)                             \
      _Pragma("unroll") for (int n_ = 0; n_ < 4; ++n_)                           \
        acc[(MH) * 4 + q_][n_] = __builtin_amdgcn_mfma_f32_16x16x32_bf16(        \
            af_[q_], bfr[n_], acc[(MH) * 4 + q_][n_], 0, 0, 0);                  \
    __builtin_amdgcn_s_setprio(0);                                               \
  } while (0)

#define PHE(RA, RB, MH, READB, VMSTMT, ...) do {                                 \
    s16x8 af_[4];                                                                \
    _Pragma("unroll") for (int q_ = 0; q_ < 4; ++q_)                             \
      af_[q_] = *(const s16x8*)((RA) + aoff + ((MH) * 4 + q_) * 512);            \
    if (READB) {                                                                 \
      _Pragma("unroll") for (int n_ = 0; n_ < 4; ++n_)                           \
        bfr[n_] = *(const s16x8*)((RB) + boff + n_ * 512);                       \
    }                                                                            \
    __VA_ARGS__;                                                                 \
    VMSTMT;                                                                      \
    __builtin_amdgcn_sched_barrier(0);                                           \
    __builtin_amdgcn_s_barrier();                                                \
    asm volatile("s_waitcnt lgkmcnt(0)" ::: "memory");                           \
    __builtin_amdgcn_sched_barrier(0);                                           \
    __builtin_amdgcn_s_setprio(1);                                               \
    _Pragma("unroll") for (int q_ = 0; q_ < 4; ++q_)                             \
      _Pragma("unroll") for (int n_ = 0; n_ < 4; ++n_)                           \
        acc[(MH) * 4 + q_][n_] = __builtin_amdgcn_mfma_f32_16x16x32_bf16(        \
            af_[q_], bfr[n_], acc[(MH) * 4 + q_][n_], 0, 0, 0);                  \
    __builtin_amdgcn_s_setprio(0);                                               \
  } while (0)

  if constexpr (TAPS == 9) {
    mkbase(0, a0c, a1c);
    mkbase(1, a0n, a1n);
    STA8(A0k0, a0c, a1c, 0);  STB8(B0k0, 0);
    STA8(A0k1, a0c, a1c, 32); STB8(B0k1, 32);
    VM4;
    __builtin_amdgcn_s_barrier();
#pragma unroll 1
    for (int tap = 0; tap < 8; ++tap) {
      PHO(A0k0, B0k0, 0, 1, STA8(A1k0, a0c, a1c, 64));
      PHE(A0k0, B0k0, 1, 0, VM4, STB8(B1k0, 64));
      PHO(A0k1, B0k1, 0, 1, STA8(A1k1, a0c, a1c, 96));
      PHE(A0k1, B0k1, 1, 0, VM4, STB8(B1k1, 96));
      PHO(A1k0, B1k0, 0, 1, STA8(A0k0, a0c, a1c, 128));
      PHE(A1k0, B1k0, 1, 0, VM4, STB8(B0k0, 128));
      PHO(A1k1, B1k1, 0, 1, STA8(A0k1, a0c, a1c, 160));
      PHE(A1k1, B1k1, 1, 0, VM4, STB8(B0k1, 160));
      PHO(A0k0, B0k0, 0, 1, STA8(A1k0, a0c, a1c, 192));
      PHE(A0k0, B0k0, 1, 0, VM4, STB8(B1k0, 192));
      PHO(A0k1, B0k1, 0, 1, STA8(A1k1, a0c, a1c, 224));
      PHE(A0k1, B0k1, 1, 0, VM4, STB8(B1k1, 224));
      PHO(A1k0, B1k0, 0, 1, STA8(A0k0, a0n, a1n, 0));
      PHE(A1k0, B1k0, 1, 0, VM4, STB8(B0k0, 256));
      PHO(A1k1, B1k1, 0, 1, STA8(A0k1, a0n, a1n, 32));
      PHE(A1k1, B1k1, 1, 0, VM4, STB8(B0k1, 288));
      a0c = a0n; a1c = a1n;
      if (tap + 2 < 9) mkbase(tap + 2, a0n, a1n);
      Bb0 += 256; Bb1 += 256;
    }
    PHO(A0k0, B0k0, 0, 1, STA8(A1k0, a0c, a1c, 64));
    PHE(A0k0, B0k0, 1, 0, VM4, STB8(B1k0, 64));
    PHO(A0k1, B0k1, 0, 1, STA8(A1k1, a0c, a1c, 96));
    PHE(A0k1, B0k1, 1, 0, VM4, STB8(B1k1, 96));
    PHO(A1k0, B1k0, 0, 1, STA8(A0k0, a0c, a1c, 128));
    PHE(A1k0, B1k0, 1, 0, VM4, STB8(B0k0, 128));
    PHO(A1k1, B1k1, 0, 1, STA8(A0k1, a0c, a1c, 160));
    PHE(A1k1, B1k1, 1, 0, VM4, STB8(B0k1, 160));
    PHO(A0k0, B0k0, 0, 1, STA8(A1k0, a0c, a1c, 192));
    PHE(A0k0, B0k0, 1, 0, VM4, STB8(B1k0, 192));
    PHO(A0k1, B0k1, 0, 1, STA8(A1k1, a0c, a1c, 224));
    PHE(A0k1, B0k1, 1, 0, VM4, STB8(B1k1, 224));
    PHO(A1k0, B1k0, 0, 1, );
    PHE(A1k0, B1k0, 1, 0, VM0, );
    PHO(A1k1, B1k1, 0, 1, );
    PHE(A1k1, B1k1, 1, 0, NVMs, );
  } else {
    STA8(A0k0, Aa0, Aa1, 0);  STB8(B0k0, 0);
    STA8(A0k1, Aa0, Aa1, 32); STB8(B0k1, 32);
    VM4;
    __builtin_amdgcn_s_barrier();
    PHO(A0k0, B0k0, 0, 1, STA8(A1k0, Aa0, Aa1, 64));
    PHE(A0k0, B0k0, 1, 0, VM4, STB8(B1k0, 64));
    PHO(A0k1, B0k1, 0, 1, STA8(A1k1, Aa0, Aa1, 96));
    PHE(A0k1, B0k1, 1, 0, VM4, STB8(B1k1, 96));
    PHO(A1k0, B1k0, 0, 1, STA8(A0k0, Aa0, Aa1, 128));
    PHE(A1k0, B1k0, 1, 0, VM4, STB8(B0k0, 128));
    PHO(A1k1, B1k1, 0, 1, STA8(A0k1, Aa0, Aa1, 160));
    PHE(A1k1, B1k1, 1, 0, VM4, STB8(B0k1, 160));
    PHO(A0k0, B0k0, 0, 1, STA8(A1k0, Aa0, Aa1, 192));
    PHE(A0k0, B0k0, 1, 0, VM4, STB8(B1k0, 192));
    PHO(A0k1, B0k1, 0, 1, STA8(A1k1, Aa0, Aa1, 224));
    PHE(A0k1, B0k1, 1, 0, VM4, STB8(B1k1, 224));
    PHO(A1k0, B1k0, 0, 1, );
    PHE(A1k0, B1k0, 1, 0, VM0, );
    PHO(A1k1, B1k1, 0, 1, );
    PHE(A1k1, B1k1, 1, 0, NVMs, );
  }
#undef PHO
#undef PHE
#undef STA8
#undef STB8
#undef NVMs
#undef VM4
#undef VM0

  if (EPI == 2) {
    float* TR = (float*)arena;
    const int bN = t0 >> 16, hN = (t0 >> 8) & 255;
#pragma unroll 1
    for (int chunk = 0; chunk < 2; ++chunk) {
      __builtin_amdgcn_s_barrier();
      if ((wc >> 1) == chunk) {
#pragma unroll
        for (int m = 0; m < 8; ++m)
#pragma unroll
          for (int n = 0; n < 4; ++n) {
            const int col = wc * 64 + n * 16 + fr;
            const int cl  = (wc & 1) * 64 + n * 16 + fr;
            const float bb = bias[col];
#pragma unroll
            for (int j = 0; j < 4; ++j) {
              const int row = wr * 128 + m * 16 + fq * 4 + j;
              const size_t t = (size_t)t0 + row;
              TR[cl * 259 + row] = acc[m][n][j] + bb +
                                   __bfloat162float(ident[t * 256 + col]);
            }
          }
      }
      __builtin_amdgcn_s_barrier();
      {
        const int cl = tid >> 2, wo = (tid & 3) * 4;
        const int c = chunk * 128 + cl;
        float* dp = outf + (((size_t)bN * 256 + c) * 256 + hN) * 256;
#pragma unroll
        for (int q = 0; q < 16; ++q)
          *(f32x4*)(dp + wo + q * 16) = *(const f32x4*)&TR[cl * 259 + wo + q * 16];
      }
    }
    return;
  }

#pragma unroll
  for (int m = 0; m < 8; ++m) {
#pragma unroll
    for (int n = 0; n < 4; ++n) {
      const int col = wc * 64 + n * 16 + fr;
#pragma unroll
      for (int j = 0; j < 4; ++j) {
        const int row = wr * 128 + m * 16 + fq * 4 + j;
        const size_t t = (size_t)t0 + row;
        outb[t * ldo + col] = __float2bfloat16(acc[m][n][j] + bias[col]);
      }
    }
  }
}

// ---------------- 3-buffer GEMM (kept for cfeat conv, CIN=32) ----------------
template <int CIN, int TAPS, int EPI>
__global__ void __launch_bounds__(256, 2)
k_gemm(const bf16* __restrict__ Ain, const bf16* __restrict__ BT,
       const float* __restrict__ bias,
       bf16* __restrict__ outb, int ldo,
       const bf16* __restrict__ ident,
       const bf16* __restrict__ zp, int NY)
{
  constexpr int KTOT = TAPS * CIN;
  constexpr int NK = KTOT / 32;
  int t0, n0;
  remap_tile(blockIdx.x, gridDim.x, NY, 256, t0, n0);
  const int tid = threadIdx.x;
  const int wave = tid >> 6, lane = tid & 63;
  const int seg = lane & 3;
  const int rr  = lane >> 2;

  __shared__ bf16 sA0[256 * 32];
  __shared__ bf16 sA1[256 * 32];
  __shared__ bf16 sA2[256 * 32];
  __shared__ bf16 sB0[128 * 32];
  __shared__ bf16 sB1[128 * 32];
  __shared__ bf16 sB2[128 * 32];

  f32x4 acc[8][4] = {};

  const int wr = wave >> 1, wc = wave & 1;
  const int fr = lane & 15, fq = lane >> 4;
  const int sseg = (seg ^ ((rr >> 1) & 3)) * 8;
  const int slot = (fq ^ ((fr >> 1) & 3)) * 8;

#define STAGE(WA, WB, KSV) do {                                                 \
    const int k0_ = (KSV) * 32;                                                 \
    const int tap_ = k0_ / CIN;                                                 \
    const int c0_ = k0_ - tap_ * CIN;                                           \
    const int dy_ = tap_ / 3 - 1, dx_ = tap_ % 3 - 1;                           \
    _Pragma("unroll") for (int i_ = 0; i_ < 4; ++i_) {                          \
      const int g_ = i_ * 4 + wave;                                             \
      const int t_ = t0 + g_ * 16 + rr;                                         \
      const bf16* src_;                                                         \
      if (TAPS == 1) {                                                          \
        src_ = Ain + (size_t)t_ * CIN + k0_ + sseg;                             \
      } else {                                                                  \
        const int hh_ = ((t_ >> 8) & 255) + dy_, ww_ = (t_ & 255) + dx_;        \
        const bool v_ = ((unsigned)hh_ < 256u) && ((unsigned)ww_ < 256u);       \
        const long gi_ = (long)t_ + dy_ * Wimg + dx_;                           \
        src_ = v_ ? (Ain + gi_ * CIN + c0_ + sseg) : (zp + sseg);               \
      }                                                                         \
      gld16(WA + g_ * 16 * 32, src_);                                           \
    }                                                                           \
    _Pragma("unroll") for (int i_ = 0; i_ < 2; ++i_) {                          \
      const int g_ = i_ * 4 + wave;                                             \
      gld16(WB + g_ * 16 * 32,                                                  \
            BT + (size_t)(n0 + g_ * 16 + rr) * KTOT + k0_ + sseg);              \
    }                                                                           \
  } while (0)

#define GSTEP(RA, RB, WA, WB, KSV, LASTF) do {                                  \
    if (LASTF) { asm volatile("s_waitcnt vmcnt(0)" ::: "memory"); }             \
    else       { asm volatile("s_waitcnt vmcnt(6)" ::: "memory"); }             \
    __builtin_amdgcn_s_barrier();                                               \
    s16x8 af_[8], bf_[4];                                                       \
    _Pragma("unroll") for (int m_ = 0; m_ < 8; ++m_)                            \
      af_[m_] = *(const s16x8*)(RA + (wr * 128 + m_ * 16 + fr) * 32 + slot);    \
    _Pragma("unroll") for (int n_ = 0; n_ < 4; ++n_)                            \
      bf_[n_] = *(const s16x8*)(RB + (wc * 64 + n_ * 16 + fr) * 32 + slot);     \
    if ((KSV) + 2 < NK) STAGE(WA, WB, (KSV) + 2);                               \
    __builtin_amdgcn_s_setprio(1);                                              \
    _Pragma("unroll") for (int m_ = 0; m_ < 8; ++m_)                            \
      _Pragma("unroll") for (int n_ = 0; n_ < 4; ++n_)                          \
        acc[m_][n_] = __builtin_amdgcn_mfma_f32_16x16x32_bf16(af_[m_], bf_[n_], acc[m_][n_], 0, 0, 0); \
    __builtin_amdgcn_s_setprio(0);                                              \
  } while (0)

  STAGE(sA0, sB0, 0);
  STAGE(sA1, sB1, 1);

  constexpr int NMAIN = ((NK - 1) / 3) * 3;
  int ks = 0;
#pragma unroll 1
  for (; ks < NMAIN; ks += 3) {
    GSTEP(sA0, sB0, sA2, sB2, ks,     false);
    GSTEP(sA1, sB1, sA0, sB0, ks + 1, false);
    GSTEP(sA2, sB2, sA1, sB1, ks + 2, false);
  }
  constexpr int TREM = NK - NMAIN;
  if constexpr (TREM == 3) {
    GSTEP(sA0, sB0, sA2, sB2, NMAIN,     false);
    GSTEP(sA1, sB1, sA0, sB0, NMAIN + 1, false);
    GSTEP(sA2, sB2, sA1, sB1, NMAIN + 2, true);
  } else if constexpr (TREM == 2) {
    GSTEP(sA0, sB0, sA2, sB2, NMAIN,     false);
    GSTEP(sA1, sB1, sA0, sB0, NMAIN + 1, true);
  } else {
    GSTEP(sA0, sB0, sA2, sB2, NMAIN,     true);
  }
#undef GSTEP
#undef STAGE

#pragma unroll
  for (int m = 0; m < 8; ++m) {
#pragma unroll
    for (int n = 0; n < 4; ++n) {
      const int col = n0 + wc * 64 + n * 16 + fr;
#pragma unroll
      for (int j = 0; j < 4; ++j) {
        const int row = wr * 128 + m * 16 + fq * 4 + j;
        const size_t t = (size_t)t0 + row;
        float v = acc[m][n][j] + bias[col];
        if (EPI == 0) {
          outb[t * ldo + col] = __float2bfloat16(v);
        } else {
          v += __bfloat162float(ident[t * 256 + col]);
          outb[t * 256 + col] = __float2bfloat16(v);
        }
      }
    }
  }
}

// ---------------- gated dual GEMM (static triple-buffer pipeline + swizzle) ----------------
__global__ void __launch_bounds__(256, 2)
k_gemm_qkv(const bf16* __restrict__ Am, const bf16* __restrict__ Af,
           const bf16* __restrict__ Bm, const bf16* __restrict__ Bf,
           const float* __restrict__ bm, const float* __restrict__ bfi,
           bf16* __restrict__ out)
{
  int t0, n0;
  remap_tile(blockIdx.x, gridDim.x, 4, 128, t0, n0);
  const int tid = threadIdx.x;
  const int wave = tid >> 6, lane = tid & 63;
  const int seg = lane & 3;
  const int rr  = lane >> 2;

  __shared__ bf16 sA0[128 * 32];
  __shared__ bf16 sA1[128 * 32];
  __shared__ bf16 sA2[128 * 32];
  __shared__ bf16 sB0[128 * 32];
  __shared__ bf16 sB1[128 * 32];
  __shared__ bf16 sB2[128 * 32];

  f32x4 accm[4][4] = {};
  f32x4 accf[4][4] = {};

  const int wr = wave >> 1, wc = wave & 1;
  const int fr = lane & 15, fq = lane >> 4;
  const int sseg = (seg ^ ((rr >> 1) & 3)) * 8;
  const int slot = (fq ^ ((fr >> 1) & 3)) * 8;

#define STAGEQ(WA, WB, SV) do {                                                 \
    const int k0_ = ((SV) >> 1) * 32;                                           \
    const bf16* A_ = ((SV) & 1) ? Af : Am;                                      \
    const bf16* B_ = ((SV) & 1) ? Bf : Bm;                                      \
    _Pragma("unroll") for (int i_ = 0; i_ < 2; ++i_) {                          \
      const int r_ = wave * 32 + i_ * 16 + rr;                                  \
      gld16(WA + (wave * 32 + i_ * 16) * 32, A_ + (size_t)(t0 + r_) * 256 + k0_ + sseg); \
      gld16(WB + (wave * 32 + i_ * 16) * 32, B_ + (size_t)(n0 + r_) * 256 + k0_ + sseg); \
    }                                                                           \
  } while (0)

#define QSTEP(RA, RB, WA, WB, SV, LASTF) do {                                   \
    if (LASTF) { asm volatile("s_waitcnt vmcnt(0)" ::: "memory"); }             \
    else       { asm volatile("s_waitcnt vmcnt(4)" ::: "memory"); }             \
    __builtin_amdgcn_s_barrier();                                               \
    s16x8 af_[4], bf_[4];                                                       \
    _Pragma("unroll") for (int m_ = 0; m_ < 4; ++m_)                            \
      af_[m_] = *(const s16x8*)(RA + (wr * 64 + m_ * 16 + fr) * 32 + slot);     \
    _Pragma("unroll") for (int n_ = 0; n_ < 4; ++n_)                            \
      bf_[n_] = *(const s16x8*)(RB + (wc * 64 + n_ * 16 + fr) * 32 + slot);     \
    if ((SV) + 2 < 16) STAGEQ(WA, WB, (SV) + 2);                                \
    __builtin_amdgcn_s_setprio(1);                                              \
    if ((SV) & 1) {                                                             \
      _Pragma("unroll") for (int m_ = 0; m_ < 4; ++m_)                          \
        _Pragma("unroll") for (int n_ = 0; n_ < 4; ++n_)                        \
          accf[m_][n_] = __builtin_amdgcn_mfma_f32_16x16x32_bf16(af_[m_], bf_[n_], accf[m_][n_], 0, 0, 0); \
    } else {                                                                    \
      _Pragma("unroll") for (int m_ = 0; m_ < 4; ++m_)                          \
        _Pragma("unroll") for (int n_ = 0; n_ < 4; ++n_)                        \
          accm[m_][n_] = __builtin_amdgcn_mfma_f32_16x16x32_bf16(af_[m_], bf_[n_], accm[m_][n_], 0, 0, 0); \
    }                                                                           \
    __builtin_amdgcn_s_setprio(0);                                              \
  } while (0)

  STAGEQ(sA0, sB0, 0);
  STAGEQ(sA1, sB1, 1);

  int s = 0;
#pragma unroll 1
  for (; s < 15; s += 3) {
    QSTEP(sA0, sB0, sA2, sB2, s,     false);
    QSTEP(sA1, sB1, sA0, sB0, s + 1, false);
    QSTEP(sA2, sB2, sA1, sB1, s + 2, false);
  }
  QSTEP(sA0, sB0, sA2, sB2, 15, true);
#undef QSTEP
#undef STAGEQ

#pragma unroll
  for (int m = 0; m < 4; ++m) {
#pragma unroll
    for (int n = 0; n < 4; ++n) {
      const int col = n0 + wc * 64 + n * 16 + fr;
#pragma unroll
      for (int j = 0; j < 4; ++j) {
        const int row = wr * 64 + m * 16 + fq * 4 + j;
        const size_t t = (size_t)t0 + row;
        float v = accm[m][n][j] + bm[col];
        const float g = accf[m][n][j] + bfi[col];
        v *= 1.f / (1.f + __expf(-g));
        out[t * 768 + col] = __float2bfloat16(v);
      }
    }
  }
}

// ---------------- MFMA window attention (coalesced LDS staging) ----------------
__global__ void __launch_bounds__(256, 4)
k_attn_mfma(const bf16* __restrict__ qkv, bf16* __restrict__ out) {
  __shared__ short smem[4 * 7424];   // 14848 B per wave
  const int tid = threadIdx.x;
  const int wave = tid >> 6, lane = tid & 63;
  const int fr = lane & 15, fq = lane >> 4;
  const int wi = blockIdx.x >> 1;
  const int head = (blockIdx.x & 1) * 4 + wave;
  const int b = wi >> 10, rem = wi & 1023, wh = rem >> 5, ww = rem & 31;
  const size_t tbase = (size_t)b * HWimg + (size_t)(wh * 8) * Wimg + ww * 8;

  short* Qs = smem + wave * 7424;     // [64][40]
  short* Ks = Qs + 2560;              // [64][40]
  short* VT = Qs + 5120;              // [32][72]
  short* P  = Qs;                     // [64][72] alias
  short* Ol = Qs;                     // [64][40] alias

  auto tok = [&](int i) -> size_t {
    return tbase + (size_t)(i >> 3) * Wimg + (i & 7);
  };

  {
    const bf16* tb = qkv + tok(lane) * 768 + head * 32;
#pragma unroll
    for (int c = 0; c < 4; ++c) {
      s16x8 qv = *(const s16x8*)(tb + c * 8);
      s16x8 kv = *(const s16x8*)(tb + 256 + c * 8);
      s16x8 vv = *(const s16x8*)(tb + 512 + c * 8);
      *(s16x8*)(Qs + lane * 40 + c * 8) = qv;
      *(s16x8*)(Ks + lane * 40 + c * 8) = kv;
#pragma unroll
      for (int e = 0; e < 8; ++e) VT[(c * 8 + e) * 72 + lane] = vv[e];
    }
  }

  s16x8 kf[4], qf[4];
#pragma unroll
  for (int m = 0; m < 4; ++m)
    kf[m] = *(const s16x8*)(Ks + (fr + 16 * m) * 40 + fq * 8);
#pragma unroll
  for (int n = 0; n < 4; ++n)
    qf[n] = *(const s16x8*)(Qs + (fr + 16 * n) * 40 + fq * 8);

  f32x4 st[4][4] = {};
#pragma unroll
  for (int m = 0; m < 4; ++m)
#pragma unroll
    for (int n = 0; n < 4; ++n)
      st[m][n] = __builtin_amdgcn_mfma_f32_16x16x32_bf16(kf[m], qf[n], st[m][n], 0, 0, 0);

  const float scale = 0.17677669529663688f;  // 1/sqrt(32)
  float invs[4];
#pragma unroll
  for (int n = 0; n < 4; ++n) {
    float mx = -1e30f;
#pragma unroll
    for (int m = 0; m < 4; ++m)
#pragma unroll
      for (int j = 0; j < 4; ++j) mx = fmaxf(mx, st[m][n][j]);
    mx = fmaxf(mx, __shfl_xor(mx, 16));
    mx = fmaxf(mx, __shfl_xor(mx, 32));
    float sum = 0.f;
#pragma unroll
    for (int m = 0; m < 4; ++m) {
      s16x4 pk;
#pragma unroll
      for (int j = 0; j < 4; ++j) {
        float e = __expf((st[m][n][j] - mx) * scale);
        sum += e;
        pk[j] = (short)f2u(e);
      }
      *(s16x4*)(P + (fr + 16 * n) * 72 + 16 * m + 4 * fq) = pk;
    }
    sum += __shfl_xor(sum, 16);
    sum += __shfl_xor(sum, 32);
    invs[n] = 1.f / sum;
  }

  f32x4 oc[4][2] = {};
#pragma unroll
  for (int ks = 0; ks < 2; ++ks) {
    s16x8 pf[4], vf[2];
#pragma unroll
    for (int m = 0; m < 4; ++m)
      pf[m] = *(const s16x8*)(P + (fr + 16 * m) * 72 + ks * 32 + fq * 8);
#pragma unroll
    for (int n = 0; n < 2; ++n)
      vf[n] = *(const s16x8*)(VT + (fr + 16 * n) * 72 + ks * 32 + fq * 8);
#pragma unroll
    for (int m = 0; m < 4; ++m)
#pragma unroll
      for (int n = 0; n < 2; ++n)
        oc[m][n] = __builtin_amdgcn_mfma_f32_16x16x32_bf16(pf[m], vf[n], oc[m][n], 0, 0, 0);
  }

#pragma unroll
  for (int m = 0; m < 4; ++m)
#pragma unroll
    for (int j = 0; j < 4; ++j) {
      const float inv = __shfl(invs[m], 4 * fq + j);
      const int q = 16 * m + 4 * fq + j;
#pragma unroll
      for (int n = 0; n < 2; ++n)
        Ol[q * 40 + fr + 16 * n] = (short)f2u(oc[m][n][j] * inv);
    }
  {
    bf16* op = out + tok(lane) * 256 + head * 32;
#pragma unroll
    for (int c = 0; c < 4; ++c)
      *(s16x8*)(op + c * 8) = *(const s16x8*)(Ol + lane * 40 + c * 8);
  }
}

// ---------------- host ----------------
extern "C" void kernel_launch(void* const* d_in, const int* in_sizes, int n_in,
                              void* d_out, int out_size, void* d_ws, size_t ws_size,
                              hipStream_t stream) {
  const float* xmap    = (const float*)d_in[0];
  const float* xfeat   = (const float*)d_in[1];
  const float* cmap_w  = (const float*)d_in[2];
  const float* cmap_b  = (const float*)d_in[3];
  const float* cfeat_w = (const float*)d_in[4];
  const float* cfeat_b = (const float*)d_in[5];
  const float* qxmap_w = (const float*)d_in[6];
  const float* qxmap_b = (const float*)d_in[7];
  const float* kxmap_w = (const float*)d_in[8];
  const float* kxmap_b = (const float*)d_in[9];
  const float* vxmap_w = (const float*)d_in[10];
  const float* vxmap_b = (const float*)d_in[11];
  const float* qxfeat_w = (const float*)d_in[12];
  const float* qxfeat_b = (const float*)d_in[13];
  const float* kxfeat_w = (const float*)d_in[14];
  const float* kxfeat_b = (const float*)d_in[15];
  const float* proj_w  = (const float*)d_in[16];
  const float* proj_b  = (const float*)d_in[17];
  const float* cout_w  = (const float*)d_in[18];
  const float* cout_b  = (const float*)d_in[19];

  uint8_t* ws = (uint8_t*)d_ws;
  size_t off = 0;
  auto alloc = [&](size_t bytes) -> void* {
    void* p = ws + off;
    off += (bytes + 255) & ~(size_t)255;
    return p;
  };
  float* zp       = (float*)alloc(4096);
  bf16* cmap_wT   = (bf16*)alloc((size_t)2304 * 256 * 2);
  bf16* cout_wT   = (bf16*)alloc((size_t)2304 * 256 * 2);
  bf16* cfeat_wT  = (bf16*)alloc((size_t)288 * 256 * 2);
  bf16* lin_qkv_wT= (bf16*)alloc((size_t)768 * 256 * 2);
  bf16* lin_f_wT  = (bf16*)alloc((size_t)512 * 256 * 2);
  bf16* proj_wT   = (bf16*)alloc((size_t)256 * 256 * 2);
  float* bias_qkv = (float*)alloc(768 * 4);
  float* bias_f   = (float*)alloc(512 * 4);
  bf16* xm_nhwc   = (bf16*)alloc((size_t)Ttok * 256 * 2);
  bf16* xf_nhwc   = (bf16*)alloc((size_t)Ttok * 32 * 2);
  bf16* xc        = (bf16*)alloc((size_t)Ttok * 256 * 2);
  bf16* fc        = (bf16*)alloc((size_t)Ttok * 256 * 2);
  bf16* qkv       = (bf16*)alloc((size_t)Ttok * 768 * 2);
  bf16* attn_out  = xm_nhwc;          // reuse (dead after cmap conv)
  bf16* proj_out  = fc;               // reuse (dead after qkv GEMMs)
  bf16* zpb = (bf16*)zp;

  k_zero4k<<<4, 256, 0, stream>>>(zp);
  k_permconv<<<(256 * 9 * 256 + 255) / 256, 256, 0, stream>>>(cmap_w, cmap_wT, 256);
  k_permconv<<<(256 * 9 * 256 + 255) / 256, 256, 0, stream>>>(cout_w, cout_wT, 256);
  k_permconv<<<(256 * 9 * 32 + 255) / 256, 256, 0, stream>>>(cfeat_w, cfeat_wT, 32);
  k_castf2b<<<256, 256, 0, stream>>>(qxmap_w, lin_qkv_wT, 65536);
  k_castf2b<<<256, 256, 0, stream>>>(kxmap_w, lin_qkv_wT + 65536, 65536);
  k_castf2b<<<256, 256, 0, stream>>>(vxmap_w, lin_qkv_wT + 131072, 65536);
  k_castf2b<<<256, 256, 0, stream>>>(qxfeat_w, lin_f_wT, 65536);
  k_castf2b<<<256, 256, 0, stream>>>(kxfeat_w, lin_f_wT + 65536, 65536);
  k_castf2b<<<256, 256, 0, stream>>>(proj_w, proj_wT, 65536);
  k_copyf<<<1, 256, 0, stream>>>(qxmap_b, bias_qkv, 256);
  k_copyf<<<1, 256, 0, stream>>>(kxmap_b, bias_qkv + 256, 256);
  k_copyf<<<1, 256, 0, stream>>>(vxmap_b, bias_qkv + 512, 256);
  k_copyf<<<1, 256, 0, stream>>>(qxfeat_b, bias_f, 256);
  k_copyf<<<1, 256, 0, stream>>>(kxfeat_b, bias_f + 256, 256);

  k_tohwc<<<dim3(Bimg * Himg, Wimg / 32, 256 / 32), 256, 0, stream>>>(xmap, xm_nhwc, 256);
  k_tohwc<<<dim3(Bimg * Himg, Wimg / 32, 1), 256, 0, stream>>>(xfeat, xf_nhwc, 32);

  const int NB = Ttok / 256;   // 1024 blocks for 8-phase kernels (BN=256, NY=1)
  // conv cmap -> xc
  k_gemm8<9, 0><<<dim3(NB), dim3(512), 0, stream>>>(
      xm_nhwc, cmap_wT, cmap_b, xc, 256, nullptr, nullptr, zpb);
  // conv cfeat -> fc (CIN=32, 3-buffer structure)
  k_gemm<32, 9, 0><<<dim3(NB * 2), dim3(256), 0, stream>>>(
      xf_nhwc, cfeat_wT, cfeat_b, fc, 256, nullptr, zpb, 2);
  // v-linear -> qkv[:,512:768]
  k_gemm8<1, 0><<<dim3(NB), dim3(512), 0, stream>>>(
      xc, lin_qkv_wT + 131072, bias_qkv + 512, qkv + 512, 768, nullptr, nullptr, zpb);
  // gated q,k -> qkv[:,0:512] (fused dual GEMM)
  k_gemm_qkv<<<dim3((Ttok / 128) * 4), dim3(256), 0, stream>>>(
      xc, fc, lin_qkv_wT, lin_f_wT, bias_qkv, bias_f, qkv);
  // MFMA window attention
  k_attn_mfma<<<dim3(4096 * 2), dim3(256), 0, stream>>>(qkv, attn_out);
  // proj GEMM
  k_gemm8<1, 0><<<dim3(NB), dim3(512), 0, stream>>>(
      attn_out, proj_wT, proj_b, proj_out, 256, nullptr, nullptr, zpb);
  // conv cout + bias + identity -> d_out NCHW fp32 directly (fused transpose)
  k_gemm8<9, 2><<<dim3(NB), dim3(512), 0, stream>>>(
      proj_out, cout_wT, cout_b, nullptr, 0, (float*)d_out, xc, zpb);
}

// Round 17
// 1391.688 us; speedup vs baseline: 2.2179x; 1.0086x over previous
//
#include <hip/hip_runtime.h>
#include <hip/hip_bf16.h>
#include <cstdint>
#include <math.h>

using bf16 = __hip_bfloat16;
typedef __attribute__((ext_vector_type(4))) float f32x4;
typedef __attribute__((ext_vector_type(8))) short s16x8;
typedef __attribute__((ext_vector_type(4))) short s16x4;

#define AS3(p) ((__attribute__((address_space(3))) void *)(p))
#define AS1(p) ((const __attribute__((address_space(1))) void *)(p))

static constexpr int Himg = 256, Wimg = 256, Bimg = 4;
static constexpr int HWimg = Himg * Wimg;
static constexpr int Ttok = Bimg * HWimg;   // 262144 tokens

__device__ __forceinline__ void gld16(bf16* lds, const bf16* g) {
  __builtin_amdgcn_global_load_lds(AS1(g), AS3(lds), 16, 0, 0);
}

__device__ __forceinline__ unsigned short f2u(float f) {
  bf16 b = __float2bfloat16(f);
  unsigned short u; __builtin_memcpy(&u, &b, 2); return u;
}

// XCD-chunked remap (1D): hw round-robin (bid%8) -> contiguous logical chunks.
__device__ __forceinline__ int remap_lin(int bid, int total) {
  return (bid & 7) * (total >> 3) + (bid >> 3);
}
__device__ __forceinline__ void remap_tile(int bid, int total, int NY, int BMv, int& t0, int& n0) {
  int lin = remap_lin(bid, total);
  t0 = (lin / NY) * BMv;
  n0 = (lin % NY) * 128;
}

// ---------------- prep kernels ----------------
__global__ void k_zero4k(float* p) {
  p[blockIdx.x * 256 + threadIdx.x] = 0.f;
}

__global__ void k_castf2b(const float* __restrict__ s, bf16* __restrict__ d, int n) {
  int i = blockIdx.x * 256 + threadIdx.x;
  if (i < n) d[i] = __float2bfloat16(s[i]);
}

__global__ void k_copyf(const float* __restrict__ s, float* __restrict__ d, int n) {
  int i = blockIdx.x * 256 + threadIdx.x;
  if (i < n) d[i] = s[i];
}

// conv weight permute: OIHW fp32 -> [O][tap][I] bf16
__global__ void k_permconv(const float* __restrict__ w, bf16* __restrict__ o, int I) {
  int idx = blockIdx.x * 256 + threadIdx.x;
  int tot = 256 * 9 * I;
  if (idx >= tot) return;
  int i   = idx % I;
  int rem = idx / I;
  int tap = rem % 9;
  int oc  = rem / 9;
  o[idx] = __float2bfloat16(w[(oc * I + i) * 9 + tap]);
}

// NCHW fp32 -> NHWC bf16
__global__ void k_tohwc(const float* __restrict__ src, bf16* __restrict__ dst, int C) {
  int bh = blockIdx.x;
  int w0 = blockIdx.y * 32;
  int c0 = blockIdx.z * 32;
  int b = bh / Himg, h = bh % Himg;
  __shared__ float tile[32][33];
  int tid = threadIdx.x;
  int x = tid & 31, y = tid >> 5;
  const float* sp = src + (size_t)b * C * HWimg + (size_t)h * Wimg;
#pragma unroll
  for (int p = 0; p < 4; ++p) {
    int cl = y + p * 8;
    tile[cl][x] = sp[(size_t)(c0 + cl) * HWimg + w0 + x];
  }
  __syncthreads();
#pragma unroll
  for (int p = 0; p < 4; ++p) {
    int wl = y + p * 8;
    dst[((size_t)bh * Wimg + w0 + wl) * C + c0 + x] = __float2bfloat16(tile[x][wl]);
  }
}

// ================= 8-phase 256x256 GEMM / implicit conv =================
// 512 threads, 8 waves (2M x 4N), per-wave 128x64 out. K-units of 32 channels.
// LDS: 8 static 16KB units, double-buffered (4 A-slots + 4 B-slots), pair
// barriers, counted vmcnt. CIN=256: taps of 8 units. CIN=32: tap == unit (9).
// EPI 0: outb[t*ldo+col] = bf16(acc+bias)
// EPI 2: d_out NCHW fp32 = acc + bias + float(ident[t*256+col])  (fused k_tochw)
template <int CIN, int TAPS, int EPI>
__global__ void __launch_bounds__(512, 1)
k_gemm8(const bf16* __restrict__ Ain, const bf16* __restrict__ BT,
        const float* __restrict__ bias,
        bf16* __restrict__ outb, int ldo, float* __restrict__ outf,
        const bf16* __restrict__ ident,
        const bf16* __restrict__ zp)
{
  constexpr int KTOT = TAPS * CIN;
  const int t0 = remap_lin(blockIdx.x, gridDim.x) * 256;
  const int tid  = threadIdx.x;
  const int wave = tid >> 6, lane = tid & 63;
  const int wr = wave >> 2, wc = wave & 3;
  const int fr = lane & 15, fq = lane >> 4;

  __shared__ __attribute__((aligned(16))) char arena[132608];
  bf16* A0k0 = (bf16*)(arena);
  bf16* A0k1 = (bf16*)(arena + 16384);
  bf16* A1k0 = (bf16*)(arena + 32768);
  bf16* A1k1 = (bf16*)(arena + 49152);
  bf16* B0k0 = (bf16*)(arena + 65536);
  bf16* B0k1 = (bf16*)(arena + 81920);
  bf16* B1k0 = (bf16*)(arena + 98304);
  bf16* B1k1 = (bf16*)(arena + 114688);

  f32x4 acc[8][4] = {};
  s16x8 bfr[4];

  const int slot8 = (fq ^ ((fr >> 1) & 3)) * 8;
  const int aoff  = (wr * 128 + fr) * 32 + slot8;
  const int boff  = (wc * 64 + fr) * 32 + slot8;
  const int ldsl  = (tid & 3) * 8;
  const int scol  = ((tid & 3) ^ ((tid >> 3) & 3)) * 8;
  const int srow  = tid >> 2;

  const bf16* Bb0 = BT + (size_t)srow * KTOT + scol;
  const bf16* Bb1 = BT + (size_t)(128 + srow) * KTOT + scol;
  const bf16* Aa0 = Ain + (size_t)(t0 + srow) * CIN + scol;
  const bf16* Aa1 = Ain + (size_t)(t0 + 128 + srow) * CIN + scol;
  const bf16 *a0c = Aa0, *a1c = Aa1, *a0n = Aa0, *a1n = Aa1;
  const int hU = (t0 >> 8) & 255;

  auto mkbase = [&](int tap, const bf16*& o0, const bf16*& o1) {
    const int dy = tap / 3 - 1, dx = tap % 3 - 1;
    const bool rowok = ((unsigned)(hU + dy)) < 256u;
    const long gb = (long)t0 + dy * Wimg + dx;
    o0 = (rowok && (unsigned)(srow + dx) < 256u)
             ? Ain + (gb + srow) * CIN + scol : zp + scol;
    o1 = (rowok && (unsigned)(128 + srow + dx) < 256u)
             ? Ain + (gb + 128 + srow) * CIN + scol : zp + scol;
  };

#define STA8(DST, P0, P1, CE) do {                                              \
    gld16(DST + srow * 32 + ldsl, (P0) + (CE));                                 \
    gld16(DST + (128 + srow) * 32 + ldsl, (P1) + (CE));                         \
  } while (0)
#define STB8(DST, KE) do {                                                      \
    gld16(DST + srow * 32 + ldsl, Bb0 + (KE));                                  \
    gld16(DST + (128 + srow) * 32 + ldsl, Bb1 + (KE));                          \
  } while (0)

#define NVMs
#define VM4 asm volatile("s_waitcnt vmcnt(4)" ::: "memory")
#define VM0 asm volatile("s_waitcnt vmcnt(0)" ::: "memory")

#define PHO(RA, RB, MH, READB, ...) do {                                         \
    s16x8 af_[4];                                                                \
    _Pragma("unroll") for (int q_ = 0; q_ < 4; ++q_)                             \
      af_[q_] = *(const s16x8*)((RA) + aoff + ((MH) * 4 + q_) * 512);            \
    if (READB) {                                                                 \
      _Pragma("unroll") for (int n_ = 0; n_ < 4; ++n_)                           \
        bfr[n_] = *(const s16x8*)((RB) + boff + n_ * 512);                       \
    }                                                                            \
    __VA_ARGS__;                                                                 \
    asm volatile("s_waitcnt lgkmcnt(0)" ::: "memory");                           \
    __builtin_amdgcn_sched_barrier(0);                                           \
    __builtin_amdgcn_s_setprio(1);                                               \
    _Pragma("unroll") for (int q_ = 0; q_ < 4; ++q_)                             \
      _Pragma("unroll") for (int n_ = 0; n_ < 4; ++n_)                           \
        acc[(MH) * 4 + q_][n_] = __builtin_amdgcn_mfma_f32_16x16x32_bf16(        \
            af_[q_], bfr[n_], acc[(MH) * 4 + q_][n_], 0, 0, 0);                  \
    __builtin_amdgcn_s_setprio(0);                                               \
  } while (0)

#define PHE(RA, RB, MH, READB, VMSTMT, ...) do {                                 \
    s16x8 af_[4];                                                                \
    _Pragma("unroll") for (int q_ = 0; q_ < 4; ++q_)                             \
      af_[q_] = *(const s16x8*)((RA) + aoff + ((MH) * 4 + q_) * 512);            \
    if (READB) {                                                                 \
      _Pragma("unroll") for (int n_ = 0; n_ < 4; ++n_)                           \
        bfr[n_] = *(const s16x8*)((RB) + boff + n_ * 512);                       \
    }                                                                            \
    __VA_ARGS__;                                                                 \
    VMSTMT;                                                                      \
    __builtin_amdgcn_sched_barrier(0);                                           \
    __builtin_amdgcn_s_barrier();                                                \
    asm volatile("s_waitcnt lgkmcnt(0)" ::: "memory");                           \
    __builtin_amdgcn_sched_barrier(0);                                           \
    __builtin_amdgcn_s_setprio(1);                                               \
    _Pragma("unroll") for (int q_ = 0; q_ < 4; ++q_)                             \
      _Pragma("unroll") for (int n_ = 0; n_ < 4; ++n_)                           \
        acc[(MH) * 4 + q_][n_] = __builtin_amdgcn_mfma_f32_16x16x32_bf16(        \
            af_[q_], bfr[n_], acc[(MH) * 4 + q_][n_], 0, 0, 0);                  \
    __builtin_amdgcn_s_setprio(0);                                               \
  } while (0)

  if constexpr (TAPS == 9 && CIN == 256) {
    mkbase(0, a0c, a1c);
    mkbase(1, a0n, a1n);
    STA8(A0k0, a0c, a1c, 0);  STB8(B0k0, 0);
    STA8(A0k1, a0c, a1c, 32); STB8(B0k1, 32);
    VM4;
    __builtin_amdgcn_s_barrier();
#pragma unroll 1
    for (int tap = 0; tap < 8; ++tap) {
      PHO(A0k0, B0k0, 0, 1, STA8(A1k0, a0c, a1c, 64));
      PHE(A0k0, B0k0, 1, 0, VM4, STB8(B1k0, 64));
      PHO(A0k1, B0k1, 0, 1, STA8(A1k1, a0c, a1c, 96));
      PHE(A0k1, B0k1, 1, 0, VM4, STB8(B1k1, 96));
      PHO(A1k0, B1k0, 0, 1, STA8(A0k0, a0c, a1c, 128));
      PHE(A1k0, B1k0, 1, 0, VM4, STB8(B0k0, 128));
      PHO(A1k1, B1k1, 0, 1, STA8(A0k1, a0c, a1c, 160));
      PHE(A1k1, B1k1, 1, 0, VM4, STB8(B0k1, 160));
      PHO(A0k0, B0k0, 0, 1, STA8(A1k0, a0c, a1c, 192));
      PHE(A0k0, B0k0, 1, 0, VM4, STB8(B1k0, 192));
      PHO(A0k1, B0k1, 0, 1, STA8(A1k1, a0c, a1c, 224));
      PHE(A0k1, B0k1, 1, 0, VM4, STB8(B1k1, 224));
      PHO(A1k0, B1k0, 0, 1, STA8(A0k0, a0n, a1n, 0));
      PHE(A1k0, B1k0, 1, 0, VM4, STB8(B0k0, 256));
      PHO(A1k1, B1k1, 0, 1, STA8(A0k1, a0n, a1n, 32));
      PHE(A1k1, B1k1, 1, 0, VM4, STB8(B0k1, 288));
      a0c = a0n; a1c = a1n;
      if (tap + 2 < 9) mkbase(tap + 2, a0n, a1n);
      Bb0 += 256; Bb1 += 256;
    }
    PHO(A0k0, B0k0, 0, 1, STA8(A1k0, a0c, a1c, 64));
    PHE(A0k0, B0k0, 1, 0, VM4, STB8(B1k0, 64));
    PHO(A0k1, B0k1, 0, 1, STA8(A1k1, a0c, a1c, 96));
    PHE(A0k1, B0k1, 1, 0, VM4, STB8(B1k1, 96));
    PHO(A1k0, B1k0, 0, 1, STA8(A0k0, a0c, a1c, 128));
    PHE(A1k0, B1k0, 1, 0, VM4, STB8(B0k0, 128));
    PHO(A1k1, B1k1, 0, 1, STA8(A0k1, a0c, a1c, 160));
    PHE(A1k1, B1k1, 1, 0, VM4, STB8(B0k1, 160));
    PHO(A0k0, B0k0, 0, 1, STA8(A1k0, a0c, a1c, 192));
    PHE(A0k0, B0k0, 1, 0, VM4, STB8(B1k0, 192));
    PHO(A0k1, B0k1, 0, 1, STA8(A1k1, a0c, a1c, 224));
    PHE(A0k1, B0k1, 1, 0, VM4, STB8(B1k1, 224));
    PHO(A1k0, B1k0, 0, 1, );
    PHE(A1k0, B1k0, 1, 0, VM0, );
    PHO(A1k1, B1k1, 0, 1, );
    PHE(A1k1, B1k1, 1, 0, NVMs, );
  } else if constexpr (TAPS == 9) {
    // CIN == 32 (cfeat): tap == K-unit; 9 unit-pairs, slots rotate mod 4.
    // Ledger: per-pair 2A (PHO) + 2B (PHE) loads, VM4 retires unit u+1's 4;
    // last staged unit (8) drained by VM0 at pair 7. Slot reuse gap = 2 barriers.
    mkbase(0, a0c, a1c);
    STA8(A0k0, a0c, a1c, 0);  STB8(B0k0, 0);
    mkbase(1, a0c, a1c);
    STA8(A0k1, a0c, a1c, 0);  STB8(B0k1, 32);
    VM4;
    __builtin_amdgcn_s_barrier();
    PHO(A0k0, B0k0, 0, 1, mkbase(2, a0c, a1c); STA8(A1k0, a0c, a1c, 0));
    PHE(A0k0, B0k0, 1, 0, VM4, STB8(B1k0, 64));
    PHO(A0k1, B0k1, 0, 1, mkbase(3, a0c, a1c); STA8(A1k1, a0c, a1c, 0));
    PHE(A0k1, B0k1, 1, 0, VM4, STB8(B1k1, 96));
    PHO(A1k0, B1k0, 0, 1, mkbase(4, a0c, a1c); STA8(A0k0, a0c, a1c, 0));
    PHE(A1k0, B1k0, 1, 0, VM4, STB8(B0k0, 128));
    PHO(A1k1, B1k1, 0, 1, mkbase(5, a0c, a1c); STA8(A0k1, a0c, a1c, 0));
    PHE(A1k1, B1k1, 1, 0, VM4, STB8(B0k1, 160));
    PHO(A0k0, B0k0, 0, 1, mkbase(6, a0c, a1c); STA8(A1k0, a0c, a1c, 0));
    PHE(A0k0, B0k0, 1, 0, VM4, STB8(B1k0, 192));
    PHO(A0k1, B0k1, 0, 1, mkbase(7, a0c, a1c); STA8(A1k1, a0c, a1c, 0));
    PHE(A0k1, B0k1, 1, 0, VM4, STB8(B1k1, 224));
    PHO(A1k0, B1k0, 0, 1, mkbase(8, a0c, a1c); STA8(A0k0, a0c, a1c, 0));
    PHE(A1k0, B1k0, 1, 0, VM4, STB8(B0k0, 256));
    PHO(A1k1, B1k1, 0, 1, );
    PHE(A1k1, B1k1, 1, 0, VM0, );
    PHO(A0k0, B0k0, 0, 1, );
    PHE(A0k0, B0k0, 1, 0, NVMs, );
  } else {
    STA8(A0k0, Aa0, Aa1, 0);  STB8(B0k0, 0);
    STA8(A0k1, Aa0, Aa1, 32); STB8(B0k1, 32);
    VM4;
    __builtin_amdgcn_s_barrier();
    PHO(A0k0, B0k0, 0, 1, STA8(A1k0, Aa0, Aa1, 64));
    PHE(A0k0, B0k0, 1, 0, VM4, STB8(B1k0, 64));
    PHO(A0k1, B0k1, 0, 1, STA8(A1k1, Aa0, Aa1, 96));
    PHE(A0k1, B0k1, 1, 0, VM4, STB8(B1k1, 96));
    PHO(A1k0, B1k0, 0, 1, STA8(A0k0, Aa0, Aa1, 128));
    PHE(A1k0, B1k0, 1, 0, VM4, STB8(B0k0, 128));
    PHO(A1k1, B1k1, 0, 1, STA8(A0k1, Aa0, Aa1, 160));
    PHE(A1k1, B1k1, 1, 0, VM4, STB8(B0k1, 160));
    PHO(A0k0, B0k0, 0, 1, STA8(A1k0, Aa0, Aa1, 192));
    PHE(A0k0, B0k0, 1, 0, VM4, STB8(B1k0, 192));
    PHO(A0k1, B0k1, 0, 1, STA8(A1k1, Aa0, Aa1, 224));
    PHE(A0k1, B0k1, 1, 0, VM4, STB8(B1k1, 224));
    PHO(A1k0, B1k0, 0, 1, );
    PHE(A1k0, B1k0, 1, 0, VM0, );
    PHO(A1k1, B1k1, 0, 1, );
    PHE(A1k1, B1k1, 1, 0, NVMs, );
  }
#undef PHO
#undef PHE
#undef STA8
#undef STB8
#undef NVMs
#undef VM4
#undef VM0

  if (EPI == 2) {
    float* TR = (float*)arena;
    const int bN = t0 >> 16, hN = (t0 >> 8) & 255;
#pragma unroll 1
    for (int chunk = 0; chunk < 2; ++chunk) {
      __builtin_amdgcn_s_barrier();
      if ((wc >> 1) == chunk) {
#pragma unroll
        for (int m = 0; m < 8; ++m)
#pragma unroll
          for (int n = 0; n < 4; ++n) {
            const int col = wc * 64 + n * 16 + fr;
            const int cl  = (wc & 1) * 64 + n * 16 + fr;
            const float bb = bias[col];
#pragma unroll
            for (int j = 0; j < 4; ++j) {
              const int row = wr * 128 + m * 16 + fq * 4 + j;
              const size_t t = (size_t)t0 + row;
              TR[cl * 259 + row] = acc[m][n][j] + bb +
                                   __bfloat162float(ident[t * 256 + col]);
            }
          }
      }
      __builtin_amdgcn_s_barrier();
      {
        const int cl = tid >> 2, wo = (tid & 3) * 4;
        const int c = chunk * 128 + cl;
        float* dp = outf + (((size_t)bN * 256 + c) * 256 + hN) * 256;
#pragma unroll
        for (int q = 0; q < 16; ++q)
          *(f32x4*)(dp + wo + q * 16) = *(const f32x4*)&TR[cl * 259 + wo + q * 16];
      }
    }
    return;
  }

#pragma unroll
  for (int m = 0; m < 8; ++m) {
#pragma unroll
    for (int n = 0; n < 4; ++n) {
      const int col = wc * 64 + n * 16 + fr;
#pragma unroll
      for (int j = 0; j < 4; ++j) {
        const int row = wr * 128 + m * 16 + fq * 4 + j;
        const size_t t = (size_t)t0 + row;
        outb[t * ldo + col] = __float2bfloat16(acc[m][n][j] + bias[col]);
      }
    }
  }
}

// ---------------- gated dual GEMM (static triple-buffer pipeline + swizzle) ----------------
__global__ void __launch_bounds__(256, 2)
k_gemm_qkv(const bf16* __restrict__ Am, const bf16* __restrict__ Af,
           const bf16* __restrict__ Bm, const bf16* __restrict__ Bf,
           const float* __restrict__ bm, const float* __restrict__ bfi,
           bf16* __restrict__ out)
{
  int t0, n0;
  remap_tile(blockIdx.x, gridDim.x, 4, 128, t0, n0);
  const int tid = threadIdx.x;
  const int wave = tid >> 6, lane = tid & 63;
  const int seg = lane & 3;
  const int rr  = lane >> 2;

  __shared__ bf16 sA0[128 * 32];
  __shared__ bf16 sA1[128 * 32];
  __shared__ bf16 sA2[128 * 32];
  __shared__ bf16 sB0[128 * 32];
  __shared__ bf16 sB1[128 * 32];
  __shared__ bf16 sB2[128 * 32];

  f32x4 accm[4][4] = {};
  f32x4 accf[4][4] = {};

  const int wr = wave >> 1, wc = wave & 1;
  const int fr = lane & 15, fq = lane >> 4;
  const int sseg = (seg ^ ((rr >> 1) & 3)) * 8;
  const int slot = (fq ^ ((fr >> 1) & 3)) * 8;

#define STAGEQ(WA, WB, SV) do {                                                 \
    const int k0_ = ((SV) >> 1) * 32;                                           \
    const bf16* A_ = ((SV) & 1) ? Af : Am;                                      \
    const bf16* B_ = ((SV) & 1) ? Bf : Bm;                                      \
    _Pragma("unroll") for (int i_ = 0; i_ < 2; ++i_) {                          \
      const int r_ = wave * 32 + i_ * 16 + rr;                                  \
      gld16(WA + (wave * 32 + i_ * 16) * 32, A_ + (size_t)(t0 + r_) * 256 + k0_ + sseg); \
      gld16(WB + (wave * 32 + i_ * 16) * 32, B_ + (size_t)(n0 + r_) * 256 + k0_ + sseg); \
    }                                                                           \
  } while (0)

#define QSTEP(RA, RB, WA, WB, SV, LASTF) do {                                   \
    if (LASTF) { asm volatile("s_waitcnt vmcnt(0)" ::: "memory"); }             \
    else       { asm volatile("s_waitcnt vmcnt(4)" ::: "memory"); }             \
    __builtin_amdgcn_s_barrier();                                               \
    s16x8 af_[4], bf_[4];                                                       \
    _Pragma("unroll") for (int m_ = 0; m_ < 4; ++m_)                            \
      af_[m_] = *(const s16x8*)(RA + (wr * 64 + m_ * 16 + fr) * 32 + slot);     \
    _Pragma("unroll") for (int n_ = 0; n_ < 4; ++n_)                            \
      bf_[n_] = *(const s16x8*)(RB + (wc * 64 + n_ * 16 + fr) * 32 + slot);     \
    if ((SV) + 2 < 16) STAGEQ(WA, WB, (SV) + 2);                                \
    __builtin_amdgcn_s_setprio(1);                                              \
    if ((SV) & 1) {                                                             \
      _Pragma("unroll") for (int m_ = 0; m_ < 4; ++m_)                          \
        _Pragma("unroll") for (int n_ = 0; n_ < 4; ++n_)                        \
          accf[m_][n_] = __builtin_amdgcn_mfma_f32_16x16x32_bf16(af_[m_], bf_[n_], accf[m_][n_], 0, 0, 0); \
    } else {                                                                    \
      _Pragma("unroll") for (int m_ = 0; m_ < 4; ++m_)                          \
        _Pragma("unroll") for (int n_ = 0; n_ < 4; ++n_)                        \
          accm[m_][n_] = __builtin_amdgcn_mfma_f32_16x16x32_bf16(af_[m_], bf_[n_], accm[m_][n_], 0, 0, 0); \
    }                                                                           \
    __builtin_amdgcn_s_setprio(0);                                              \
  } while (0)

  STAGEQ(sA0, sB0, 0);
  STAGEQ(sA1, sB1, 1);

  int s = 0;
#pragma unroll 1
  for (; s < 15; s += 3) {
    QSTEP(sA0, sB0, sA2, sB2, s,     false);
    QSTEP(sA1, sB1, sA0, sB0, s + 1, false);
    QSTEP(sA2, sB2, sA1, sB1, s + 2, false);
  }
  QSTEP(sA0, sB0, sA2, sB2, 15, true);
#undef QSTEP
#undef STAGEQ

#pragma unroll
  for (int m = 0; m < 4; ++m) {
#pragma unroll
    for (int n = 0; n < 4; ++n) {
      const int col = n0 + wc * 64 + n * 16 + fr;
#pragma unroll
      for (int j = 0; j < 4; ++j) {
        const int row = wr * 64 + m * 16 + fq * 4 + j;
        const size_t t = (size_t)t0 + row;
        float v = accm[m][n][j] + bm[col];
        const float g = accf[m][n][j] + bfi[col];
        v *= 1.f / (1.f + __expf(-g));
        out[t * 768 + col] = __float2bfloat16(v);
      }
    }
  }
}

// ---------------- MFMA window attention (coalesced LDS staging) ----------------
__global__ void __launch_bounds__(256, 4)
k_attn_mfma(const bf16* __restrict__ qkv, bf16* __restrict__ out) {
  __shared__ short smem[4 * 7424];   // 14848 B per wave
  const int tid = threadIdx.x;
  const int wave = tid >> 6, lane = tid & 63;
  const int fr = lane & 15, fq = lane >> 4;
  const int wi = blockIdx.x >> 1;
  const int head = (blockIdx.x & 1) * 4 + wave;
  const int b = wi >> 10, rem = wi & 1023, wh = rem >> 5, ww = rem & 31;
  const size_t tbase = (size_t)b * HWimg + (size_t)(wh * 8) * Wimg + ww * 8;

  short* Qs = smem + wave * 7424;     // [64][40]
  short* Ks = Qs + 2560;              // [64][40]
  short* VT = Qs + 5120;              // [32][72]
  short* P  = Qs;                     // [64][72] alias
  short* Ol = Qs;                     // [64][40] alias

  auto tok = [&](int i) -> size_t {
    return tbase + (size_t)(i >> 3) * Wimg + (i & 7);
  };

  {
    const bf16* tb = qkv + tok(lane) * 768 + head * 32;
#pragma unroll
    for (int c = 0; c < 4; ++c) {
      s16x8 qv = *(const s16x8*)(tb + c * 8);
      s16x8 kv = *(const s16x8*)(tb + 256 + c * 8);
      s16x8 vv = *(const s16x8*)(tb + 512 + c * 8);
      *(s16x8*)(Qs + lane * 40 + c * 8) = qv;
      *(s16x8*)(Ks + lane * 40 + c * 8) = kv;
#pragma unroll
      for (int e = 0; e < 8; ++e) VT[(c * 8 + e) * 72 + lane] = vv[e];
    }
  }

  s16x8 kf[4], qf[4];
#pragma unroll
  for (int m = 0; m < 4; ++m)
    kf[m] = *(const s16x8*)(Ks + (fr + 16 * m) * 40 + fq * 8);
#pragma unroll
  for (int n = 0; n < 4; ++n)
    qf[n] = *(const s16x8*)(Qs + (fr + 16 * n) * 40 + fq * 8);

  f32x4 st[4][4] = {};
#pragma unroll
  for (int m = 0; m < 4; ++m)
#pragma unroll
    for (int n = 0; n < 4; ++n)
      st[m][n] = __builtin_amdgcn_mfma_f32_16x16x32_bf16(kf[m], qf[n], st[m][n], 0, 0, 0);

  const float scale = 0.17677669529663688f;  // 1/sqrt(32)
  float invs[4];
#pragma unroll
  for (int n = 0; n < 4; ++n) {
    float mx = -1e30f;
#pragma unroll
    for (int m = 0; m < 4; ++m)
#pragma unroll
      for (int j = 0; j < 4; ++j) mx = fmaxf(mx, st[m][n][j]);
    mx = fmaxf(mx, __shfl_xor(mx, 16));
    mx = fmaxf(mx, __shfl_xor(mx, 32));
    float sum = 0.f;
#pragma unroll
    for (int m = 0; m < 4; ++m) {
      s16x4 pk;
#pragma unroll
      for (int j = 0; j < 4; ++j) {
        float e = __expf((st[m][n][j] - mx) * scale);
        sum += e;
        pk[j] = (short)f2u(e);
      }
      *(s16x4*)(P + (fr + 16 * n) * 72 + 16 * m + 4 * fq) = pk;
    }
    sum += __shfl_xor(sum, 16);
    sum += __shfl_xor(sum, 32);
    invs[n] = 1.f / sum;
  }

  f32x4 oc[4][2] = {};
#pragma unroll
  for (int ks = 0; ks < 2; ++ks) {
    s16x8 pf[4], vf[2];
#pragma unroll
    for (int m = 0; m < 4; ++m)
      pf[m] = *(const s16x8*)(P + (fr + 16 * m) * 72 + ks * 32 + fq * 8);
#pragma unroll
    for (int n = 0; n < 2; ++n)
      vf[n] = *(const s16x8*)(VT + (fr + 16 * n) * 72 + ks * 32 + fq * 8);
#pragma unroll
    for (int m = 0; m < 4; ++m)
#pragma unroll
      for (int n = 0; n < 2; ++n)
        oc[m][n] = __builtin_amdgcn_mfma_f32_16x16x32_bf16(pf[m], vf[n], oc[m][n], 0, 0, 0);
  }

#pragma unroll
  for (int m = 0; m < 4; ++m)
#pragma unroll
    for (int j = 0; j < 4; ++j) {
      const float inv = __shfl(invs[m], 4 * fq + j);
      const int q = 16 * m + 4 * fq + j;
#pragma unroll
      for (int n = 0; n < 2; ++n)
        Ol[q * 40 + fr + 16 * n] = (short)f2u(oc[m][n][j] * inv);
    }
  {
    bf16* op = out + tok(lane) * 256 + head * 32;
#pragma unroll
    for (int c = 0; c < 4; ++c)
      *(s16x8*)(op + c * 8) = *(const s16x8*)(Ol + lane * 40 + c * 8);
  }
}

// ---------------- host ----------------
extern "C" void kernel_launch(void* const* d_in, const int* in_sizes, int n_in,
                              void* d_out, int out_size, void* d_ws, size_t ws_size,
                              hipStream_t stream) {
  const float* xmap    = (const float*)d_in[0];
  const float* xfeat   = (const float*)d_in[1];
  const float* cmap_w  = (const float*)d_in[2];
  const float* cmap_b  = (const float*)d_in[3];
  const float* cfeat_w = (const float*)d_in[4];
  const float* cfeat_b = (const float*)d_in[5];
  const float* qxmap_w = (const float*)d_in[6];
  const float* qxmap_b = (const float*)d_in[7];
  const float* kxmap_w = (const float*)d_in[8];
  const float* kxmap_b = (const float*)d_in[9];
  const float* vxmap_w = (const float*)d_in[10];
  const float* vxmap_b = (const float*)d_in[11];
  const float* qxfeat_w = (const float*)d_in[12];
  const float* qxfeat_b = (const float*)d_in[13];
  const float* kxfeat_w = (const float*)d_in[14];
  const float* kxfeat_b = (const float*)d_in[15];
  const float* proj_w  = (const float*)d_in[16];
  const float* proj_b  = (const float*)d_in[17];
  const float* cout_w  = (const float*)d_in[18];
  const float* cout_b  = (const float*)d_in[19];

  uint8_t* ws = (uint8_t*)d_ws;
  size_t off = 0;
  auto alloc = [&](size_t bytes) -> void* {
    void* p = ws + off;
    off += (bytes + 255) & ~(size_t)255;
    return p;
  };
  float* zp       = (float*)alloc(4096);
  bf16* cmap_wT   = (bf16*)alloc((size_t)2304 * 256 * 2);
  bf16* cout_wT   = (bf16*)alloc((size_t)2304 * 256 * 2);
  bf16* cfeat_wT  = (bf16*)alloc((size_t)288 * 256 * 2);
  bf16* lin_qkv_wT= (bf16*)alloc((size_t)768 * 256 * 2);
  bf16* lin_f_wT  = (bf16*)alloc((size_t)512 * 256 * 2);
  bf16* proj_wT   = (bf16*)alloc((size_t)256 * 256 * 2);
  float* bias_qkv = (float*)alloc(768 * 4);
  float* bias_f   = (float*)alloc(512 * 4);
  bf16* xm_nhwc   = (bf16*)alloc((size_t)Ttok * 256 * 2);
  bf16* xf_nhwc   = (bf16*)alloc((size_t)Ttok * 32 * 2);
  bf16* xc        = (bf16*)alloc((size_t)Ttok * 256 * 2);
  bf16* fc        = (bf16*)alloc((size_t)Ttok * 256 * 2);
  bf16* qkv       = (bf16*)alloc((size_t)Ttok * 768 * 2);
  bf16* attn_out  = xm_nhwc;          // reuse (dead after cmap conv)
  bf16* proj_out  = fc;               // reuse (dead after qkv GEMMs)
  bf16* zpb = (bf16*)zp;

  k_zero4k<<<4, 256, 0, stream>>>(zp);
  k_permconv<<<(256 * 9 * 256 + 255) / 256, 256, 0, stream>>>(cmap_w, cmap_wT, 256);
  k_permconv<<<(256 * 9 * 256 + 255) / 256, 256, 0, stream>>>(cout_w, cout_wT, 256);
  k_permconv<<<(256 * 9 * 32 + 255) / 256, 256, 0, stream>>>(cfeat_w, cfeat_wT, 32);
  k_castf2b<<<256, 256, 0, stream>>>(qxmap_w, lin_qkv_wT, 65536);
  k_castf2b<<<256, 256, 0, stream>>>(kxmap_w, lin_qkv_wT + 65536, 65536);
  k_castf2b<<<256, 256, 0, stream>>>(vxmap_w, lin_qkv_wT + 131072, 65536);
  k_castf2b<<<256, 256, 0, stream>>>(qxfeat_w, lin_f_wT, 65536);
  k_castf2b<<<256, 256, 0, stream>>>(kxfeat_w, lin_f_wT + 65536, 65536);
  k_castf2b<<<256, 256, 0, stream>>>(proj_w, proj_wT, 65536);
  k_copyf<<<1, 256, 0, stream>>>(qxmap_b, bias_qkv, 256);
  k_copyf<<<1, 256, 0, stream>>>(kxmap_b, bias_qkv + 256, 256);
  k_copyf<<<1, 256, 0, stream>>>(vxmap_b, bias_qkv + 512, 256);
  k_copyf<<<1, 256, 0, stream>>>(qxfeat_b, bias_f, 256);
  k_copyf<<<1, 256, 0, stream>>>(kxfeat_b, bias_f + 256, 256);

  k_tohwc<<<dim3(Bimg * Himg, Wimg / 32, 256 / 32), 256, 0, stream>>>(xmap, xm_nhwc, 256);
  k_tohwc<<<dim3(Bimg * Himg, Wimg / 32, 1), 256, 0, stream>>>(xfeat, xf_nhwc, 32);

  const int NB = Ttok / 256;   // 1024 blocks for 8-phase kernels (BN=256, NY=1)
  // conv cmap -> xc
  k_gemm8<256, 9, 0><<<dim3(NB), dim3(512), 0, stream>>>(
      xm_nhwc, cmap_wT, cmap_b, xc, 256, nullptr, nullptr, zpb);
  // conv cfeat -> fc (CIN=32, 9-unit 8-phase pipeline)
  k_gemm8<32, 9, 0><<<dim3(NB), dim3(512), 0, stream>>>(
      xf_nhwc, cfeat_wT, cfeat_b, fc, 256, nullptr, nullptr, zpb);
  // v-linear -> qkv[:,512:768]
  k_gemm8<256, 1, 0><<<dim3(NB), dim3(512), 0, stream>>>(
      xc, lin_qkv_wT + 131072, bias_qkv + 512, qkv + 512, 768, nullptr, nullptr, zpb);
  // gated q,k -> qkv[:,0:512] (fused dual GEMM)
  k_gemm_qkv<<<dim3((Ttok / 128) * 4), dim3(256), 0, stream>>>(
      xc, fc, lin_qkv_wT, lin_f_wT, bias_qkv, bias_f, qkv);
  // MFMA window attention
  k_attn_mfma<<<dim3(4096 * 2), dim3(256), 0, stream>>>(qkv, attn_out);
  // proj GEMM
  k_gemm8<256, 1, 0><<<dim3(NB), dim3(512), 0, stream>>>(
      attn_out, proj_wT, proj_b, proj_out, 256, nullptr, nullptr, zpb);
  // conv cout + bias + identity -> d_out NCHW fp32 directly (fused transpose)
  k_gemm8<256, 9, 2><<<dim3(NB), dim3(512), 0, stream>>>(
      proj_out, cout_wT, cout_b, nullptr, 0, (float*)d_out, xc, zpb);
}

// Round 18
// 1385.965 us; speedup vs baseline: 2.2271x; 1.0041x over previous
//
#include <hip/hip_runtime.h>
#include <hip/hip_bf16.h>
#include <cstdint>
#include <math.h>

using bf16 = __hip_bfloat16;
typedef __attribute__((ext_vector_type(4))) float f32x4;
typedef __attribute__((ext_vector_type(8))) short s16x8;
typedef __attribute__((ext_vector_type(4))) short s16x4;

#define AS3(p) ((__attribute__((address_space(3))) void *)(p))
#define AS1(p) ((const __attribute__((address_space(1))) void *)(p))

static constexpr int Himg = 256, Wimg = 256, Bimg = 4;
static constexpr int HWimg = Himg * Wimg;
static constexpr int Ttok = Bimg * HWimg;   // 262144 tokens

__device__ __forceinline__ void gld16(bf16* lds, const bf16* g) {
  __builtin_amdgcn_global_load_lds(AS1(g), AS3(lds), 16, 0, 0);
}

__device__ __forceinline__ unsigned short f2u(float f) {
  bf16 b = __float2bfloat16(f);
  unsigned short u; __builtin_memcpy(&u, &b, 2); return u;
}

// XCD-chunked remap (1D): hw round-robin (bid%8) -> contiguous logical chunks.
__device__ __forceinline__ int remap_lin(int bid, int total) {
  return (bid & 7) * (total >> 3) + (bid >> 3);
}
__device__ __forceinline__ void remap_tile(int bid, int total, int NY, int BMv, int& t0, int& n0) {
  int lin = remap_lin(bid, total);
  t0 = (lin / NY) * BMv;
  n0 = (lin % NY) * 128;
}

// ---------------- prep kernels ----------------
__global__ void k_zero4k(float* p) {
  p[blockIdx.x * 256 + threadIdx.x] = 0.f;
}

__global__ void k_castf2b(const float* __restrict__ s, bf16* __restrict__ d, int n) {
  int i = blockIdx.x * 256 + threadIdx.x;
  if (i < n) d[i] = __float2bfloat16(s[i]);
}

__global__ void k_copyf(const float* __restrict__ s, float* __restrict__ d, int n) {
  int i = blockIdx.x * 256 + threadIdx.x;
  if (i < n) d[i] = s[i];
}

// conv weight permute: OIHW fp32 -> [O][tap][I] bf16
__global__ void k_permconv(const float* __restrict__ w, bf16* __restrict__ o, int I) {
  int idx = blockIdx.x * 256 + threadIdx.x;
  int tot = 256 * 9 * I;
  if (idx >= tot) return;
  int i   = idx % I;
  int rem = idx / I;
  int tap = rem % 9;
  int oc  = rem / 9;
  o[idx] = __float2bfloat16(w[(oc * I + i) * 9 + tap]);
}

// NCHW fp32 -> NHWC bf16
__global__ void k_tohwc(const float* __restrict__ src, bf16* __restrict__ dst, int C) {
  int bh = blockIdx.x;
  int w0 = blockIdx.y * 32;
  int c0 = blockIdx.z * 32;
  int b = bh / Himg, h = bh % Himg;
  __shared__ float tile[32][33];
  int tid = threadIdx.x;
  int x = tid & 31, y = tid >> 5;
  const float* sp = src + (size_t)b * C * HWimg + (size_t)h * Wimg;
#pragma unroll
  for (int p = 0; p < 4; ++p) {
    int cl = y + p * 8;
    tile[cl][x] = sp[(size_t)(c0 + cl) * HWimg + w0 + x];
  }
  __syncthreads();
#pragma unroll
  for (int p = 0; p < 4; ++p) {
    int wl = y + p * 8;
    dst[((size_t)bh * Wimg + w0 + wl) * C + c0 + x] = __float2bfloat16(tile[x][wl]);
  }
}

// ================= 8-phase 256x256 GEMM / implicit conv =================
// 512 threads, 8 waves (2M x 4N), per-wave 128x64 out. K-units of 32 channels.
// LDS: 8 static 16KB units, double-buffered (4 A-slots + 4 B-slots), pair
// barriers, counted vmcnt. CIN=256: taps of 8 units. CIN=32: tap == unit (9).
// EPI 0: outb[t*ldo+col] = bf16(acc+bias)
// EPI 2: d_out NCHW fp32 = acc + bias + float(ident[t*256+col])  (fused k_tochw)
template <int CIN, int TAPS, int EPI>
__global__ void __launch_bounds__(512, 1)
k_gemm8(const bf16* __restrict__ Ain, const bf16* __restrict__ BT,
        const float* __restrict__ bias,
        bf16* __restrict__ outb, int ldo, float* __restrict__ outf,
        const bf16* __restrict__ ident,
        const bf16* __restrict__ zp)
{
  constexpr int KTOT = TAPS * CIN;
  const int t0 = remap_lin(blockIdx.x, gridDim.x) * 256;
  const int tid  = threadIdx.x;
  const int wave = tid >> 6, lane = tid & 63;
  const int wr = wave >> 2, wc = wave & 3;
  const int fr = lane & 15, fq = lane >> 4;

  __shared__ __attribute__((aligned(16))) char arena[132608];
  bf16* A0k0 = (bf16*)(arena);
  bf16* A0k1 = (bf16*)(arena + 16384);
  bf16* A1k0 = (bf16*)(arena + 32768);
  bf16* A1k1 = (bf16*)(arena + 49152);
  bf16* B0k0 = (bf16*)(arena + 65536);
  bf16* B0k1 = (bf16*)(arena + 81920);
  bf16* B1k0 = (bf16*)(arena + 98304);
  bf16* B1k1 = (bf16*)(arena + 114688);

  f32x4 acc[8][4] = {};
  s16x8 bfr[4];

  const int slot8 = (fq ^ ((fr >> 1) & 3)) * 8;
  const int aoff  = (wr * 128 + fr) * 32 + slot8;
  const int boff  = (wc * 64 + fr) * 32 + slot8;
  const int ldsl  = (tid & 3) * 8;
  const int scol  = ((tid & 3) ^ ((tid >> 3) & 3)) * 8;
  const int srow  = tid >> 2;

  const bf16* Bb0 = BT + (size_t)srow * KTOT + scol;
  const bf16* Bb1 = BT + (size_t)(128 + srow) * KTOT + scol;
  const bf16* Aa0 = Ain + (size_t)(t0 + srow) * CIN + scol;
  const bf16* Aa1 = Ain + (size_t)(t0 + 128 + srow) * CIN + scol;
  const bf16 *a0c = Aa0, *a1c = Aa1, *a0n = Aa0, *a1n = Aa1;
  const int hU = (t0 >> 8) & 255;

  auto mkbase = [&](int tap, const bf16*& o0, const bf16*& o1) {
    const int dy = tap / 3 - 1, dx = tap % 3 - 1;
    const bool rowok = ((unsigned)(hU + dy)) < 256u;
    const long gb = (long)t0 + dy * Wimg + dx;
    o0 = (rowok && (unsigned)(srow + dx) < 256u)
             ? Ain + (gb + srow) * CIN + scol : zp + scol;
    o1 = (rowok && (unsigned)(128 + srow + dx) < 256u)
             ? Ain + (gb + 128 + srow) * CIN + scol : zp + scol;
  };

#define STA8(DST, P0, P1, CE) do {                                              \
    gld16(DST + srow * 32 + ldsl, (P0) + (CE));                                 \
    gld16(DST + (128 + srow) * 32 + ldsl, (P1) + (CE));                         \
  } while (0)
#define STB8(DST, KE) do {                                                      \
    gld16(DST + srow * 32 + ldsl, Bb0 + (KE));                                  \
    gld16(DST + (128 + srow) * 32 + ldsl, Bb1 + (KE));                          \
  } while (0)

#define NVMs
#define VM4 asm volatile("s_waitcnt vmcnt(4)" ::: "memory")
#define VM0 asm volatile("s_waitcnt vmcnt(0)" ::: "memory")

#define PHO(RA, RB, MH, READB, ...) do {                                         \
    s16x8 af_[4];                                                                \
    _Pragma("unroll") for (int q_ = 0; q_ < 4; ++q_)                             \
      af_[q_] = *(const s16x8*)((RA) + aoff + ((MH) * 4 + q_) * 512);            \
    if (READB) {                                                                 \
      _Pragma("unroll") for (int n_ = 0; n_ < 4; ++n_)                           \
        bfr[n_] = *(const s16x8*)((RB) + boff + n_ * 512);                       \
    }                                                                            \
    __VA_ARGS__;                                                                 \
    asm volatile("s_waitcnt lgkmcnt(0)" ::: "memory");                           \
    __builtin_amdgcn_sched_barrier(0);                                           \
    __builtin_amdgcn_s_setprio(1);                                               \
    _Pragma("unroll") for (int q_ = 0; q_ < 4; ++q_)                             \
      _Pragma("unroll") for (int n_ = 0; n_ < 4; ++n_)                           \
        acc[(MH) * 4 + q_][n_] = __builtin_amdgcn_mfma_f32_16x16x32_bf16(        \
            af_[q_], bfr[n_], acc[(MH) * 4 + q_][n_], 0, 0, 0);                  \
    __builtin_amdgcn_s_setprio(0);                                               \
  } while (0)

#define PHE(RA, RB, MH, READB, VMSTMT, ...) do {                                 \
    s16x8 af_[4];                                                                \
    _Pragma("unroll") for (int q_ = 0; q_ < 4; ++q_)                             \
      af_[q_] = *(const s16x8*)((RA) + aoff + ((MH) * 4 + q_) * 512);            \
    if (READB) {                                                                 \
      _Pragma("unroll") for (int n_ = 0; n_ < 4; ++n_)                           \
        bfr[n_] = *(const s16x8*)((RB) + boff + n_ * 512);                       \
    }                                                                            \
    __VA_ARGS__;                                                                 \
    VMSTMT;                                                                      \
    __builtin_amdgcn_sched_barrier(0);                                           \
    __builtin_amdgcn_s_barrier();                                                \
    asm volatile("s_waitcnt lgkmcnt(0)" ::: "memory");                           \
    __builtin_amdgcn_sched_barrier(0);                                           \
    __builtin_amdgcn_s_setprio(1);                                               \
    _Pragma("unroll") for (int q_ = 0; q_ < 4; ++q_)                             \
      _Pragma("unroll") for (int n_ = 0; n_ < 4; ++n_)                           \
        acc[(MH) * 4 + q_][n_] = __builtin_amdgcn_mfma_f32_16x16x32_bf16(        \
            af_[q_], bfr[n_], acc[(MH) * 4 + q_][n_], 0, 0, 0);                  \
    __builtin_amdgcn_s_setprio(0);                                               \
  } while (0)

  if constexpr (TAPS == 9 && CIN == 256) {
    mkbase(0, a0c, a1c);
    mkbase(1, a0n, a1n);
    STA8(A0k0, a0c, a1c, 0);  STB8(B0k0, 0);
    STA8(A0k1, a0c, a1c, 32); STB8(B0k1, 32);
    VM4;
    __builtin_amdgcn_s_barrier();
#pragma unroll 1
    for (int tap = 0; tap < 8; ++tap) {
      PHO(A0k0, B0k0, 0, 1, STA8(A1k0, a0c, a1c, 64));
      PHE(A0k0, B0k0, 1, 0, VM4, STB8(B1k0, 64));
      PHO(A0k1, B0k1, 0, 1, STA8(A1k1, a0c, a1c, 96));
      PHE(A0k1, B0k1, 1, 0, VM4, STB8(B1k1, 96));
      PHO(A1k0, B1k0, 0, 1, STA8(A0k0, a0c, a1c, 128));
      PHE(A1k0, B1k0, 1, 0, VM4, STB8(B0k0, 128));
      PHO(A1k1, B1k1, 0, 1, STA8(A0k1, a0c, a1c, 160));
      PHE(A1k1, B1k1, 1, 0, VM4, STB8(B0k1, 160));
      PHO(A0k0, B0k0, 0, 1, STA8(A1k0, a0c, a1c, 192));
      PHE(A0k0, B0k0, 1, 0, VM4, STB8(B1k0, 192));
      PHO(A0k1, B0k1, 0, 1, STA8(A1k1, a0c, a1c, 224));
      PHE(A0k1, B0k1, 1, 0, VM4, STB8(B1k1, 224));
      PHO(A1k0, B1k0, 0, 1, STA8(A0k0, a0n, a1n, 0));
      PHE(A1k0, B1k0, 1, 0, VM4, STB8(B0k0, 256));
      PHO(A1k1, B1k1, 0, 1, STA8(A0k1, a0n, a1n, 32));
      PHE(A1k1, B1k1, 1, 0, VM4, STB8(B0k1, 288));
      a0c = a0n; a1c = a1n;
      if (tap + 2 < 9) mkbase(tap + 2, a0n, a1n);
      Bb0 += 256; Bb1 += 256;
    }
    PHO(A0k0, B0k0, 0, 1, STA8(A1k0, a0c, a1c, 64));
    PHE(A0k0, B0k0, 1, 0, VM4, STB8(B1k0, 64));
    PHO(A0k1, B0k1, 0, 1, STA8(A1k1, a0c, a1c, 96));
    PHE(A0k1, B0k1, 1, 0, VM4, STB8(B1k1, 96));
    PHO(A1k0, B1k0, 0, 1, STA8(A0k0, a0c, a1c, 128));
    PHE(A1k0, B1k0, 1, 0, VM4, STB8(B0k0, 128));
    PHO(A1k1, B1k1, 0, 1, STA8(A0k1, a0c, a1c, 160));
    PHE(A1k1, B1k1, 1, 0, VM4, STB8(B0k1, 160));
    PHO(A0k0, B0k0, 0, 1, STA8(A1k0, a0c, a1c, 192));
    PHE(A0k0, B0k0, 1, 0, VM4, STB8(B1k0, 192));
    PHO(A0k1, B0k1, 0, 1, STA8(A1k1, a0c, a1c, 224));
    PHE(A0k1, B0k1, 1, 0, VM4, STB8(B1k1, 224));
    PHO(A1k0, B1k0, 0, 1, );
    PHE(A1k0, B1k0, 1, 0, VM0, );
    PHO(A1k1, B1k1, 0, 1, );
    PHE(A1k1, B1k1, 1, 0, NVMs, );
  } else if constexpr (TAPS == 9) {
    // CIN == 32 (cfeat): tap == K-unit; 9 unit-pairs, slots rotate mod 4.
    mkbase(0, a0c, a1c);
    STA8(A0k0, a0c, a1c, 0);  STB8(B0k0, 0);
    mkbase(1, a0c, a1c);
    STA8(A0k1, a0c, a1c, 0);  STB8(B0k1, 32);
    VM4;
    __builtin_amdgcn_s_barrier();
    PHO(A0k0, B0k0, 0, 1, mkbase(2, a0c, a1c); STA8(A1k0, a0c, a1c, 0));
    PHE(A0k0, B0k0, 1, 0, VM4, STB8(B1k0, 64));
    PHO(A0k1, B0k1, 0, 1, mkbase(3, a0c, a1c); STA8(A1k1, a0c, a1c, 0));
    PHE(A0k1, B0k1, 1, 0, VM4, STB8(B1k1, 96));
    PHO(A1k0, B1k0, 0, 1, mkbase(4, a0c, a1c); STA8(A0k0, a0c, a1c, 0));
    PHE(A1k0, B1k0, 1, 0, VM4, STB8(B0k0, 128));
    PHO(A1k1, B1k1, 0, 1, mkbase(5, a0c, a1c); STA8(A0k1, a0c, a1c, 0));
    PHE(A1k1, B1k1, 1, 0, VM4, STB8(B0k1, 160));
    PHO(A0k0, B0k0, 0, 1, mkbase(6, a0c, a1c); STA8(A1k0, a0c, a1c, 0));
    PHE(A0k0, B0k0, 1, 0, VM4, STB8(B1k0, 192));
    PHO(A0k1, B0k1, 0, 1, mkbase(7, a0c, a1c); STA8(A1k1, a0c, a1c, 0));
    PHE(A0k1, B0k1, 1, 0, VM4, STB8(B1k1, 224));
    PHO(A1k0, B1k0, 0, 1, mkbase(8, a0c, a1c); STA8(A0k0, a0c, a1c, 0));
    PHE(A1k0, B1k0, 1, 0, VM4, STB8(B0k0, 256));
    PHO(A1k1, B1k1, 0, 1, );
    PHE(A1k1, B1k1, 1, 0, VM0, );
    PHO(A0k0, B0k0, 0, 1, );
    PHE(A0k0, B0k0, 1, 0, NVMs, );
  } else {
    STA8(A0k0, Aa0, Aa1, 0);  STB8(B0k0, 0);
    STA8(A0k1, Aa0, Aa1, 32); STB8(B0k1, 32);
    VM4;
    __builtin_amdgcn_s_barrier();
    PHO(A0k0, B0k0, 0, 1, STA8(A1k0, Aa0, Aa1, 64));
    PHE(A0k0, B0k0, 1, 0, VM4, STB8(B1k0, 64));
    PHO(A0k1, B0k1, 0, 1, STA8(A1k1, Aa0, Aa1, 96));
    PHE(A0k1, B0k1, 1, 0, VM4, STB8(B1k1, 96));
    PHO(A1k0, B1k0, 0, 1, STA8(A0k0, Aa0, Aa1, 128));
    PHE(A1k0, B1k0, 1, 0, VM4, STB8(B0k0, 128));
    PHO(A1k1, B1k1, 0, 1, STA8(A0k1, Aa0, Aa1, 160));
    PHE(A1k1, B1k1, 1, 0, VM4, STB8(B0k1, 160));
    PHO(A0k0, B0k0, 0, 1, STA8(A1k0, Aa0, Aa1, 192));
    PHE(A0k0, B0k0, 1, 0, VM4, STB8(B1k0, 192));
    PHO(A0k1, B0k1, 0, 1, STA8(A1k1, Aa0, Aa1, 224));
    PHE(A0k1, B0k1, 1, 0, VM4, STB8(B1k1, 224));
    PHO(A1k0, B1k0, 0, 1, );
    PHE(A1k0, B1k0, 1, 0, VM0, );
    PHO(A1k1, B1k1, 0, 1, );
    PHE(A1k1, B1k1, 1, 0, NVMs, );
  }
#undef PHO
#undef PHE
#undef STA8
#undef STB8
#undef NVMs
#undef VM4
#undef VM0

  if (EPI == 2) {
    float* TR = (float*)arena;
    const int bN = t0 >> 16, hN = (t0 >> 8) & 255;
#pragma unroll 1
    for (int chunk = 0; chunk < 2; ++chunk) {
      __builtin_amdgcn_s_barrier();
      if ((wc >> 1) == chunk) {
#pragma unroll
        for (int m = 0; m < 8; ++m)
#pragma unroll
          for (int n = 0; n < 4; ++n) {
            const int col = wc * 64 + n * 16 + fr;
            const int cl  = (wc & 1) * 64 + n * 16 + fr;
            const float bb = bias[col];
#pragma unroll
            for (int j = 0; j < 4; ++j) {
              const int row = wr * 128 + m * 16 + fq * 4 + j;
              const size_t t = (size_t)t0 + row;
              TR[cl * 259 + row] = acc[m][n][j] + bb +
                                   __bfloat162float(ident[t * 256 + col]);
            }
          }
      }
      __builtin_amdgcn_s_barrier();
      {
        const int cl = tid >> 2, wo = (tid & 3) * 4;
        const int c = chunk * 128 + cl;
        float* dp = outf + (((size_t)bN * 256 + c) * 256 + hN) * 256;
#pragma unroll
        for (int q = 0; q < 16; ++q)
          *(f32x4*)(dp + wo + q * 16) = *(const f32x4*)&TR[cl * 259 + wo + q * 16];
      }
    }
    return;
  }

#pragma unroll
  for (int m = 0; m < 8; ++m) {
#pragma unroll
    for (int n = 0; n < 4; ++n) {
      const int col = wc * 64 + n * 16 + fr;
#pragma unroll
      for (int j = 0; j < 4; ++j) {
        const int row = wr * 128 + m * 16 + fq * 4 + j;
        const size_t t = (size_t)t0 + row;
        outb[t * ldo + col] = __float2bfloat16(acc[m][n][j] + bias[col]);
      }
    }
  }
}

// ---- gated dual GEMM: 4+4-buffer pair-barrier pipeline (k_gemm8 ledger) ----
// 16 unit-pairs: unit p = (p&1 ? feat : map, khalf p>>1). Pair p consumes
// sA[p%4]/sB[p%4], PHO stages A of unit p+2 + 8 MFMA (m=0,1), PHE stages B +
// VM4 + barrier + 8 MFMA (m=2,3). Stage-ahead 2, VM4 leaves this pair's 4
// loads in flight; buffer reuse gap = 2 barriers (same proof as k_gemm8).
__global__ void __launch_bounds__(256, 2)
k_gemm_qkv(const bf16* __restrict__ Am, const bf16* __restrict__ Af,
           const bf16* __restrict__ Bm, const bf16* __restrict__ Bf,
           const float* __restrict__ bm, const float* __restrict__ bfi,
           bf16* __restrict__ out)
{
  int t0, n0;
  remap_tile(blockIdx.x, gridDim.x, 4, 128, t0, n0);
  const int tid = threadIdx.x;
  const int wave = tid >> 6, lane = tid & 63;
  const int seg = lane & 3;
  const int rr  = lane >> 2;

  __shared__ bf16 sA0[128 * 32];
  __shared__ bf16 sA1[128 * 32];
  __shared__ bf16 sA2[128 * 32];
  __shared__ bf16 sA3[128 * 32];
  __shared__ bf16 sB0[128 * 32];
  __shared__ bf16 sB1[128 * 32];
  __shared__ bf16 sB2[128 * 32];
  __shared__ bf16 sB3[128 * 32];

  f32x4 accm[4][4] = {};
  f32x4 accf[4][4] = {};
  s16x8 bfr[4];

  const int wr = wave >> 1, wc = wave & 1;
  const int fr = lane & 15, fq = lane >> 4;
  const int sseg = (seg ^ ((rr >> 1) & 3)) * 8;
  const int slot = (fq ^ ((fr >> 1) & 3)) * 8;

#define STQA(DST, AP, K0) do {                                                  \
    _Pragma("unroll") for (int i_ = 0; i_ < 2; ++i_)                            \
      gld16(DST + (wave * 32 + i_ * 16) * 32,                                   \
            (AP) + (size_t)(t0 + wave * 32 + i_ * 16 + rr) * 256 + (K0) + sseg);\
  } while (0)
#define STQB(DST, BP, K0) do {                                                  \
    _Pragma("unroll") for (int i_ = 0; i_ < 2; ++i_)                            \
      gld16(DST + (wave * 32 + i_ * 16) * 32,                                   \
            (BP) + (size_t)(n0 + wave * 32 + i_ * 16 + rr) * 256 + (K0) + sseg);\
  } while (0)

#define NVMs
#define VM4 asm volatile("s_waitcnt vmcnt(4)" ::: "memory")
#define VM0 asm volatile("s_waitcnt vmcnt(0)" ::: "memory")

#define PHOQ(RA, RB, ACC, ...) do {                                             \
    s16x8 af_[2];                                                               \
    _Pragma("unroll") for (int m_ = 0; m_ < 2; ++m_)                            \
      af_[m_] = *(const s16x8*)((RA) + (wr * 64 + m_ * 16 + fr) * 32 + slot);   \
    _Pragma("unroll") for (int n_ = 0; n_ < 4; ++n_)                            \
      bfr[n_] = *(const s16x8*)((RB) + (wc * 64 + n_ * 16 + fr) * 32 + slot);   \
    __VA_ARGS__;                                                                \
    asm volatile("s_waitcnt lgkmcnt(0)" ::: "memory");                          \
    __builtin_amdgcn_sched_barrier(0);                                          \
    __builtin_amdgcn_s_setprio(1);                                              \
    _Pragma("unroll") for (int m_ = 0; m_ < 2; ++m_)                            \
      _Pragma("unroll") for (int n_ = 0; n_ < 4; ++n_)                          \
        ACC[m_][n_] = __builtin_amdgcn_mfma_f32_16x16x32_bf16(                  \
            af_[m_], bfr[n_], ACC[m_][n_], 0, 0, 0);                            \
    __builtin_amdgcn_s_setprio(0);                                              \
  } while (0)

#define PHEQ(RA, ACC, VMSTMT, ...) do {                                         \
    s16x8 af_[2];                                                               \
    _Pragma("unroll") for (int m_ = 0; m_ < 2; ++m_)                            \
      af_[m_] = *(const s16x8*)((RA) + (wr * 64 + (2 + m_) * 16 + fr) * 32 + slot); \
    __VA_ARGS__;                                                                \
    VMSTMT;                                                                     \
    __builtin_amdgcn_sched_barrier(0);                                          \
    __builtin_amdgcn_s_barrier();                                               \
    asm volatile("s_waitcnt lgkmcnt(0)" ::: "memory");                          \
    __builtin_amdgcn_sched_barrier(0);                                          \
    __builtin_amdgcn_s_setprio(1);                                              \
    _Pragma("unroll") for (int m_ = 0; m_ < 2; ++m_)                            \
      _Pragma("unroll") for (int n_ = 0; n_ < 4; ++n_)                          \
        ACC[2 + m_][n_] = __builtin_amdgcn_mfma_f32_16x16x32_bf16(              \
            af_[m_], bfr[n_], ACC[2 + m_][n_], 0, 0, 0);                        \
    __builtin_amdgcn_s_setprio(0);                                              \
  } while (0)

  // prologue: units 0 (m,k0) and 1 (f,k0)
  STQA(sA0, Am, 0);  STQB(sB0, Bm, 0);
  STQA(sA1, Af, 0);  STQB(sB1, Bf, 0);
  VM4;
  __builtin_amdgcn_s_barrier();

  PHOQ(sA0, sB0, accm, STQA(sA2, Am, 32));
  PHEQ(sA0, accm, VM4, STQB(sB2, Bm, 32));
  PHOQ(sA1, sB1, accf, STQA(sA3, Af, 32));
  PHEQ(sA1, accf, VM4, STQB(sB3, Bf, 32));
  PHOQ(sA2, sB2, accm, STQA(sA0, Am, 64));
  PHEQ(sA2, accm, VM4, STQB(sB0, Bm, 64));
  PHOQ(sA3, sB3, accf, STQA(sA1, Af, 64));
  PHEQ(sA3, accf, VM4, STQB(sB1, Bf, 64));
  PHOQ(sA0, sB0, accm, STQA(sA2, Am, 96));
  PHEQ(sA0, accm, VM4, STQB(sB2, Bm, 96));
  PHOQ(sA1, sB1, accf, STQA(sA3, Af, 96));
  PHEQ(sA1, accf, VM4, STQB(sB3, Bf, 96));
  PHOQ(sA2, sB2, accm, STQA(sA0, Am, 128));
  PHEQ(sA2, accm, VM4, STQB(sB0, Bm, 128));
  PHOQ(sA3, sB3, accf, STQA(sA1, Af, 128));
  PHEQ(sA3, accf, VM4, STQB(sB1, Bf, 128));
  PHOQ(sA0, sB0, accm, STQA(sA2, Am, 160));
  PHEQ(sA0, accm, VM4, STQB(sB2, Bm, 160));
  PHOQ(sA1, sB1, accf, STQA(sA3, Af, 160));
  PHEQ(sA1, accf, VM4, STQB(sB3, Bf, 160));
  PHOQ(sA2, sB2, accm, STQA(sA0, Am, 192));
  PHEQ(sA2, accm, VM4, STQB(sB0, Bm, 192));
  PHOQ(sA3, sB3, accf, STQA(sA1, Af, 192));
  PHEQ(sA3, accf, VM4, STQB(sB1, Bf, 192));
  PHOQ(sA0, sB0, accm, STQA(sA2, Am, 224));
  PHEQ(sA0, accm, VM4, STQB(sB2, Bm, 224));
  PHOQ(sA1, sB1, accf, STQA(sA3, Af, 224));
  PHEQ(sA1, accf, VM4, STQB(sB3, Bf, 224));
  PHOQ(sA2, sB2, accm, );
  PHEQ(sA2, accm, VM0, );
  PHOQ(sA3, sB3, accf, );
  PHEQ(sA3, accf, NVMs, );

#undef PHOQ
#undef PHEQ
#undef STQA
#undef STQB
#undef NVMs
#undef VM4
#undef VM0

#pragma unroll
  for (int m = 0; m < 4; ++m) {
#pragma unroll
    for (int n = 0; n < 4; ++n) {
      const int col = n0 + wc * 64 + n * 16 + fr;
#pragma unroll
      for (int j = 0; j < 4; ++j) {
        const int row = wr * 64 + m * 16 + fq * 4 + j;
        const size_t t = (size_t)t0 + row;
        float v = accm[m][n][j] + bm[col];
        const float g = accf[m][n][j] + bfi[col];
        v *= 1.f / (1.f + __expf(-g));
        out[t * 768 + col] = __float2bfloat16(v);
      }
    }
  }
}

// ---------------- MFMA window attention (coalesced LDS staging) ----------------
__global__ void __launch_bounds__(256, 4)
k_attn_mfma(const bf16* __restrict__ qkv, bf16* __restrict__ out) {
  __shared__ short smem[4 * 7424];   // 14848 B per wave
  const int tid = threadIdx.x;
  const int wave = tid >> 6, lane = tid & 63;
  const int fr = lane & 15, fq = lane >> 4;
  const int wi = blockIdx.x >> 1;
  const int head = (blockIdx.x & 1) * 4 + wave;
  const int b = wi >> 10, rem = wi & 1023, wh = rem >> 5, ww = rem & 31;
  const size_t tbase = (size_t)b * HWimg + (size_t)(wh * 8) * Wimg + ww * 8;

  short* Qs = smem + wave * 7424;     // [64][40]
  short* Ks = Qs + 2560;              // [64][40]
  short* VT = Qs + 5120;              // [32][72]
  short* P  = Qs;                     // [64][72] alias
  short* Ol = Qs;                     // [64][40] alias

  auto tok = [&](int i) -> size_t {
    return tbase + (size_t)(i >> 3) * Wimg + (i & 7);
  };

  {
    const bf16* tb = qkv + tok(lane) * 768 + head * 32;
#pragma unroll
    for (int c = 0; c < 4; ++c) {
      s16x8 qv = *(const s16x8*)(tb + c * 8);
      s16x8 kv = *(const s16x8*)(tb + 256 + c * 8);
      s16x8 vv = *(const s16x8*)(tb + 512 + c * 8);
      *(s16x8*)(Qs + lane * 40 + c * 8) = qv;
      *(s16x8*)(Ks + lane * 40 + c * 8) = kv;
#pragma unroll
      for (int e = 0; e < 8; ++e) VT[(c * 8 + e) * 72 + lane] = vv[e];
    }
  }

  s16x8 kf[4], qf[4];
#pragma unroll
  for (int m = 0; m < 4; ++m)
    kf[m] = *(const s16x8*)(Ks + (fr + 16 * m) * 40 + fq * 8);
#pragma unroll
  for (int n = 0; n < 4; ++n)
    qf[n] = *(const s16x8*)(Qs + (fr + 16 * n) * 40 + fq * 8);

  f32x4 st[4][4] = {};
#pragma unroll
  for (int m = 0; m < 4; ++m)
#pragma unroll
    for (int n = 0; n < 4; ++n)
      st[m][n] = __builtin_amdgcn_mfma_f32_16x16x32_bf16(kf[m], qf[n], st[m][n], 0, 0, 0);

  const float scale = 0.17677669529663688f;  // 1/sqrt(32)
  float invs[4];
#pragma unroll
  for (int n = 0; n < 4; ++n) {
    float mx = -1e30f;
#pragma unroll
    for (int m = 0; m < 4; ++m)
#pragma unroll
      for (int j = 0; j < 4; ++j) mx = fmaxf(mx, st[m][n][j]);
    mx = fmaxf(mx, __shfl_xor(mx, 16));
    mx = fmaxf(mx, __shfl_xor(mx, 32));
    float sum = 0.f;
#pragma unroll
    for (int m = 0; m < 4; ++m) {
      s16x4 pk;
#pragma unroll
      for (int j = 0; j < 4; ++j) {
        float e = __expf((st[m][n][j] - mx) * scale);
        sum += e;
        pk[j] = (short)f2u(e);
      }
      *(s16x4*)(P + (fr + 16 * n) * 72 + 16 * m + 4 * fq) = pk;
    }
    sum += __shfl_xor(sum, 16);
    sum += __shfl_xor(sum, 32);
    invs[n] = 1.f / sum;
  }

  f32x4 oc[4][2] = {};
#pragma unroll
  for (int ks = 0; ks < 2; ++ks) {
    s16x8 pf[4], vf[2];
#pragma unroll
    for (int m = 0; m < 4; ++m)
      pf[m] = *(const s16x8*)(P + (fr + 16 * m) * 72 + ks * 32 + fq * 8);
#pragma unroll
    for (int n = 0; n < 2; ++n)
      vf[n] = *(const s16x8*)(VT + (fr + 16 * n) * 72 + ks * 32 + fq * 8);
#pragma unroll
    for (int m = 0; m < 4; ++m)
#pragma unroll
      for (int n = 0; n < 2; ++n)
        oc[m][n] = __builtin_amdgcn_mfma_f32_16x16x32_bf16(pf[m], vf[n], oc[m][n], 0, 0, 0);
  }

#pragma unroll
  for (int m = 0; m < 4; ++m)
#pragma unroll
    for (int j = 0; j < 4; ++j) {
      const float inv = __shfl(invs[m], 4 * fq + j);
      const int q = 16 * m + 4 * fq + j;
#pragma unroll
      for (int n = 0; n < 2; ++n)
        Ol[q * 40 + fr + 16 * n] = (short)f2u(oc[m][n][j] * inv);
    }
  {
    bf16* op = out + tok(lane) * 256 + head * 32;
#pragma unroll
    for (int c = 0; c < 4; ++c)
      *(s16x8*)(op + c * 8) = *(const s16x8*)(Ol + lane * 40 + c * 8);
  }
}

// ---------------- host ----------------
extern "C" void kernel_launch(void* const* d_in, const int* in_sizes, int n_in,
                              void* d_out, int out_size, void* d_ws, size_t ws_size,
                              hipStream_t stream) {
  const float* xmap    = (const float*)d_in[0];
  const float* xfeat   = (const float*)d_in[1];
  const float* cmap_w  = (const float*)d_in[2];
  const float* cmap_b  = (const float*)d_in[3];
  const float* cfeat_w = (const float*)d_in[4];
  const float* cfeat_b = (const float*)d_in[5];
  const float* qxmap_w = (const float*)d_in[6];
  const float* qxmap_b = (const float*)d_in[7];
  const float* kxmap_w = (const float*)d_in[8];
  const float* kxmap_b = (const float*)d_in[9];
  const float* vxmap_w = (const float*)d_in[10];
  const float* vxmap_b = (const float*)d_in[11];
  const float* qxfeat_w = (const float*)d_in[12];
  const float* qxfeat_b = (const float*)d_in[13];
  const float* kxfeat_w = (const float*)d_in[14];
  const float* kxfeat_b = (const float*)d_in[15];
  const float* proj_w  = (const float*)d_in[16];
  const float* proj_b  = (const float*)d_in[17];
  const float* cout_w  = (const float*)d_in[18];
  const float* cout_b  = (const float*)d_in[19];

  uint8_t* ws = (uint8_t*)d_ws;
  size_t off = 0;
  auto alloc = [&](size_t bytes) -> void* {
    void* p = ws + off;
    off += (bytes + 255) & ~(size_t)255;
    return p;
  };
  float* zp       = (float*)alloc(4096);
  bf16* cmap_wT   = (bf16*)alloc((size_t)2304 * 256 * 2);
  bf16* cout_wT   = (bf16*)alloc((size_t)2304 * 256 * 2);
  bf16* cfeat_wT  = (bf16*)alloc((size_t)288 * 256 * 2);
  bf16* lin_qkv_wT= (bf16*)alloc((size_t)768 * 256 * 2);
  bf16* lin_f_wT  = (bf16*)alloc((size_t)512 * 256 * 2);
  bf16* proj_wT   = (bf16*)alloc((size_t)256 * 256 * 2);
  float* bias_qkv = (float*)alloc(768 * 4);
  float* bias_f   = (float*)alloc(512 * 4);
  bf16* xm_nhwc   = (bf16*)alloc((size_t)Ttok * 256 * 2);
  bf16* xf_nhwc   = (bf16*)alloc((size_t)Ttok * 32 * 2);
  bf16* xc        = (bf16*)alloc((size_t)Ttok * 256 * 2);
  bf16* fc        = (bf16*)alloc((size_t)Ttok * 256 * 2);
  bf16* qkv       = (bf16*)alloc((size_t)Ttok * 768 * 2);
  bf16* attn_out  = xm_nhwc;          // reuse (dead after cmap conv)
  bf16* proj_out  = fc;               // reuse (dead after qkv GEMMs)
  bf16* zpb = (bf16*)zp;

  k_zero4k<<<4, 256, 0, stream>>>(zp);
  k_permconv<<<(256 * 9 * 256 + 255) / 256, 256, 0, stream>>>(cmap_w, cmap_wT, 256);
  k_permconv<<<(256 * 9 * 256 + 255) / 256, 256, 0, stream>>>(cout_w, cout_wT, 256);
  k_permconv<<<(256 * 9 * 32 + 255) / 256, 256, 0, stream>>>(cfeat_w, cfeat_wT, 32);
  k_castf2b<<<256, 256, 0, stream>>>(qxmap_w, lin_qkv_wT, 65536);
  k_castf2b<<<256, 256, 0, stream>>>(kxmap_w, lin_qkv_wT + 65536, 65536);
  k_castf2b<<<256, 256, 0, stream>>>(vxmap_w, lin_qkv_wT + 131072, 65536);
  k_castf2b<<<256, 256, 0, stream>>>(qxfeat_w, lin_f_wT, 65536);
  k_castf2b<<<256, 256, 0, stream>>>(kxfeat_w, lin_f_wT + 65536, 65536);
  k_castf2b<<<256, 256, 0, stream>>>(proj_w, proj_wT, 65536);
  k_copyf<<<1, 256, 0, stream>>>(qxmap_b, bias_qkv, 256);
  k_copyf<<<1, 256, 0, stream>>>(kxmap_b, bias_qkv + 256, 256);
  k_copyf<<<1, 256, 0, stream>>>(vxmap_b, bias_qkv + 512, 256);
  k_copyf<<<1, 256, 0, stream>>>(qxfeat_b, bias_f, 256);
  k_copyf<<<1, 256, 0, stream>>>(kxfeat_b, bias_f + 256, 256);

  k_tohwc<<<dim3(Bimg * Himg, Wimg / 32, 256 / 32), 256, 0, stream>>>(xmap, xm_nhwc, 256);
  k_tohwc<<<dim3(Bimg * Himg, Wimg / 32, 1), 256, 0, stream>>>(xfeat, xf_nhwc, 32);

  const int NB = Ttok / 256;   // 1024 blocks for 8-phase kernels (BN=256, NY=1)
  // conv cmap -> xc
  k_gemm8<256, 9, 0><<<dim3(NB), dim3(512), 0, stream>>>(
      xm_nhwc, cmap_wT, cmap_b, xc, 256, nullptr, nullptr, zpb);
  // conv cfeat -> fc (CIN=32, 9-unit 8-phase pipeline)
  k_gemm8<32, 9, 0><<<dim3(NB), dim3(512), 0, stream>>>(
      xf_nhwc, cfeat_wT, cfeat_b, fc, 256, nullptr, nullptr, zpb);
  // v-linear -> qkv[:,512:768]
  k_gemm8<256, 1, 0><<<dim3(NB), dim3(512), 0, stream>>>(
      xc, lin_qkv_wT + 131072, bias_qkv + 512, qkv + 512, 768, nullptr, nullptr, zpb);
  // gated q,k -> qkv[:,0:512] (pair-barrier dual GEMM)
  k_gemm_qkv<<<dim3((Ttok / 128) * 4), dim3(256), 0, stream>>>(
      xc, fc, lin_qkv_wT, lin_f_wT, bias_qkv, bias_f, qkv);
  // MFMA window attention
  k_attn_mfma<<<dim3(4096 * 2), dim3(256), 0, stream>>>(qkv, attn_out);
  // proj GEMM
  k_gemm8<256, 1, 0><<<dim3(NB), dim3(512), 0, stream>>>(
      attn_out, proj_wT, proj_b, proj_out, 256, nullptr, nullptr, zpb);
  // conv cout + bias + identity -> d_out NCHW fp32 directly (fused transpose)
  k_gemm8<256, 9, 2><<<dim3(NB), dim3(512), 0, stream>>>(
      proj_out, cout_wT, cout_b, nullptr, 0, (float*)d_out, xc, zpb);
}